// Round 2
// baseline (6972.343 us; speedup 1.0000x reference)
//
#include <hip/hip_runtime.h>

// S=1024, T=64, F=128, J=64, E=256, H=4, DH=64. M = S*T = 65536 rows.
// Storage type T = float (ws >= 196 MiB) or bf16-in-ushort (ws >= 100 MiB).

typedef unsigned short hb;  // bf16 storage

__device__ inline float b2f(hb u){ return __uint_as_float(((unsigned)u)<<16); }
__device__ inline hb f2b(float x){
  unsigned a = __float_as_uint(x);
  return (hb)((a + 0x7fffu + ((a>>16)&1u)) >> 16);
}
__device__ inline float4 ld4f(const float* p){ return *(const float4*)p; }
__device__ inline float4 ld4f(const hb* p){
  ushort4 u = *(const ushort4*)p;
  return make_float4(b2f(u.x), b2f(u.y), b2f(u.z), b2f(u.w));
}
__device__ inline void st4f(float* p, float4 v){ *(float4*)p = v; }
__device__ inline void st4f(hb* p, float4 v){
  ushort4 u; u.x=f2b(v.x); u.y=f2b(v.y); u.z=f2b(v.z); u.w=f2b(v.w);
  *(ushort4*)p = u;
}
__device__ inline float ld1(const float* p){ return *p; }
__device__ inline float ld1(const hb* p){ return b2f(*p); }

__device__ inline float wave_sum(float v){
  #pragma unroll
  for (int o=32;o;o>>=1) v += __shfl_xor(v,o);
  return v;
}
__device__ inline float wave_max(float v){
  #pragma unroll
  for (int o=32;o;o>>=1) v = fmaxf(v,__shfl_xor(v,o));
  return v;
}

// ---------------------------------------------------------------- pe table
__global__ __launch_bounds__(256) void k_pe(float* __restrict__ pe){
  int t = blockIdx.x, i = threadIdx.x;
  float two_i = (float)((i>>1)<<1);
  float dv = powf(100004.0f, two_i*(1.0f/256.0f));
  float v = (float)t / dv;
  pe[t*256+i] = (i&1) ? cosf(v) : sinf(v);
}

// ---------------------------------------------------------------- gate softmax
__global__ __launch_bounds__(64) void k_gate(const float* __restrict__ x,
    const float* __restrict__ gW, const float* __restrict__ gb,
    float* __restrict__ gate){
  int s = blockIdx.x, lane = threadIdx.x;
  __shared__ float xg[64];
  xg[lane] = x[((size_t)s*64+63)*192 + 128 + lane];
  __syncthreads();
  float a0 = gb[lane], a1 = gb[64+lane];
  #pragma unroll 4
  for (int j=0;j<64;j++){
    float xv = xg[j];
    a0 += xv*gW[j*128+lane];
    a1 += xv*gW[j*128+64+lane];
  }
  float mx = wave_max(fmaxf(a0,a1));
  float e0 = __expf(a0-mx), e1 = __expf(a1-mx);
  float sm = wave_sum(e0+e1);
  gate[s*128+lane]    = e0/sm;
  gate[s*128+64+lane] = e1/sm;
}

// ---------------------------------------------------------------- pack (H,E,DH) -> (E, H*DH)
__global__ __launch_bounds__(256) void k_pack(const float* __restrict__ w0,
    const float* __restrict__ w1, const float* __restrict__ w2,
    const float* __restrict__ w3, const float* __restrict__ w4,
    const float* __restrict__ w5, float* __restrict__ pack){
  int g = blockIdx.x*256 + threadIdx.x;
  int mat = g>>16; int local = g&65535;
  int e = local>>8; int n = local&255;
  const float* src = (mat==0)?w0:(mat==1)?w1:(mat==2)?w2:(mat==3)?w3:(mat==4)?w4:w5;
  pack[g] = src[((n>>6)<<14) + (e<<6) + (n&63)];
}

// ---------------------------------------------------------------- generic GEMM
// MODE 0: C = A@B. MODE 1: C = (gate*x)@B + pe  (TI must be float).
template<typename TI, typename TO, int KDIM, int MODE>
__global__ __launch_bounds__(256) void k_gemm(
    const TI* __restrict__ A, int lda,
    const float* __restrict__ Bm, int ldb,
    TO* __restrict__ Cm, int ldc,
    const float* __restrict__ pe, const float* __restrict__ gate){
  __shared__ float As[32][68];   // [k][m]
  __shared__ float Bs[32][68];   // [k][n]
  const int tid = threadIdx.x;
  const int m0 = blockIdx.x<<6, n0 = blockIdx.y<<6;
  const int tx = tid&15, ty = tid>>4;
  float acc[4][4] = {};
  for (int k0=0; k0<KDIM; k0+=32){
    #pragma unroll
    for (int i=0;i<2;i++){
      int id = tid*2+i;
      int row = id>>3, kq = id&7;
      float4 v = ld4f(A + (size_t)(m0+row)*lda + k0 + (kq<<2));
      if (MODE==1){
        const float* gp = gate + (((m0+row)>>6)<<7) + k0 + (kq<<2);
        float4 gg = *(const float4*)gp;
        v.x*=gg.x; v.y*=gg.y; v.z*=gg.z; v.w*=gg.w;
      }
      As[(kq<<2)+0][row]=v.x; As[(kq<<2)+1][row]=v.y;
      As[(kq<<2)+2][row]=v.z; As[(kq<<2)+3][row]=v.w;
      int brow = id>>4, bq = id&15;
      *(float4*)&Bs[brow][bq<<2] =
        *(const float4*)(Bm + (size_t)(k0+brow)*ldb + n0 + (bq<<2));
    }
    __syncthreads();
    #pragma unroll
    for (int kk=0;kk<32;kk++){
      float4 a4 = *(float4*)&As[kk][ty<<2];
      float4 b4 = *(float4*)&Bs[kk][tx<<2];
      float av[4]={a4.x,a4.y,a4.z,a4.w};
      float bv[4]={b4.x,b4.y,b4.z,b4.w};
      #pragma unroll
      for (int u=0;u<4;u++)
        #pragma unroll
        for (int w=0;w<4;w++) acc[u][w] += av[u]*bv[w];
    }
    __syncthreads();
  }
  #pragma unroll
  for (int u=0;u<4;u++){
    int row = m0 + (ty<<2) + u;
    float4 o = make_float4(acc[u][0],acc[u][1],acc[u][2],acc[u][3]);
    if (MODE==1){
      float4 p4 = *(const float4*)(pe + ((row&63)<<8) + n0 + (tx<<2));
      o.x+=p4.x; o.y+=p4.y; o.z+=p4.z; o.w+=p4.w;
    }
    st4f(Cm + (size_t)row*ldc + n0 + (tx<<2), o);
  }
}

// ---------------------------------------------------------------- row LayerNorm (E=256), 4 rows/block
template<typename TI, typename TO>
__global__ __launch_bounds__(256) void k_ln(const TI* __restrict__ in,
    TO* __restrict__ out, const float* __restrict__ g,
    const float* __restrict__ b){
  const int wv = threadIdx.x>>6, lane = threadIdx.x&63;
  const size_t row = (size_t)blockIdx.x*4 + wv;
  float4 v = ld4f(in + row*256 + (lane<<2));
  float sm = wave_sum(v.x+v.y+v.z+v.w);
  float sq = wave_sum(v.x*v.x+v.y*v.y+v.z*v.z+v.w*v.w);
  float mean = sm*(1.f/256.f);
  float rs = rsqrtf(sq*(1.f/256.f) - mean*mean + 1e-10f);
  float4 gg = *(const float4*)(g + (lane<<2));
  float4 bb = *(const float4*)(b + (lane<<2));
  float4 o;
  o.x=(v.x-mean)*rs*gg.x+bb.x; o.y=(v.y-mean)*rs*gg.y+bb.y;
  o.z=(v.z-mean)*rs*gg.z+bb.z; o.w=(v.w-mean)*rs*gg.w+bb.w;
  st4f(out + row*256 + (lane<<2), o);
}

// LDS quad-index XOR swizzle
#define SWQ(row, dq) (((dq) ^ (((row)>>2)&7)))
__device__ inline float xc_read(const float (*Xc)[64], int row, int kk){
  return Xc[row][((((kk)>>2) ^ (((row)>>2)&7))<<2) | ((kk)&3)];
}

// ---------------------------------------------------------------- unified attention
// NT=1: intra, grid(s,hh). NT=16: inter flash, grid(hh,t,qc).
// FUSEQ: project Q in-kernel from full-width Xq (rows via qbase/qrs) with Wq.
// Output: O[ga] = (P@V)/(l*8) + Resid[ga]  (Resid may alias O).
// K/V compact [M][128], head col = hh*64.
template<typename T, int NT, bool FUSEQ>
__global__ __launch_bounds__(256) void k_attn(
    const T* __restrict__ Xq, const T* __restrict__ Kc, const T* __restrict__ Vc,
    const T* Resid, T* O, const float* __restrict__ Wq, int hbase){
  __shared__ float Qs[64][64], Ks[64][64], Vs[64][64];  // 48 KB
  const int tid = threadIdx.x;
  int hh, t=0, qc=0, s=0;
  if (NT==1){ s = blockIdx.x; hh = blockIdx.y; }
  else      { hh = blockIdx.x; t = blockIdx.y; qc = blockIdx.z; }
  const int gcol = (hbase+hh)<<6;      // col in full-width [M][256] tensors
  const int ccol = hh<<6;              // col in compact [M][128] K/V
  const size_t qbase = (NT==1) ? (size_t)s*16384 : ((size_t)qc*4096 + t)*256;
  const int qrs = (NT==1) ? 256 : 16384;
  const int i0 = (tid>>4)<<2;          // query rows of this 16-lane group
  const int j0 = (tid&15)<<2;          // key cols / head-dim cols
  const int tx = tid&15;

  if (FUSEQ){
    float qa[4][4] = {};
    for (int kc=0; kc<4; kc++){
      #pragma unroll
      for (int it=0; it<4; it++){
        int f4 = it*256+tid; int row=f4>>4; int cq=f4&15;
        float4 v = ld4f(Xq + qbase + (size_t)row*qrs + (kc<<6) + (cq<<2));
        *(float4*)&Ks[row][SWQ(row,cq)<<2] = v;     // Xc chunk
        *(float4*)&Vs[row][cq<<2] =                  // Wq chunk [k][d]
          *(const float4*)(Wq + (size_t)((kc<<6)+row)*256 + gcol + (cq<<2));
      }
      __syncthreads();
      for (int kk=0;kk<64;kk++){
        float4 w4 = *(float4*)&Vs[kk][j0];
        #pragma unroll
        for (int u=0;u<4;u++){
          float xv = xc_read(Ks, i0+u, kk);
          qa[u][0]+=xv*w4.x; qa[u][1]+=xv*w4.y;
          qa[u][2]+=xv*w4.z; qa[u][3]+=xv*w4.w;
        }
      }
      __syncthreads();
    }
    #pragma unroll
    for (int u=0;u<4;u++)
      *(float4*)&Qs[i0+u][SWQ(i0+u,tx)<<2] =
        make_float4(qa[u][0],qa[u][1],qa[u][2],qa[u][3]);
  } else {
    #pragma unroll
    for (int it=0; it<4; it++){
      int f4 = it*256+tid; int row=f4>>4; int cq=f4&15;
      float4 v = ld4f(Xq + qbase + (size_t)row*qrs + gcol + (cq<<2));
      *(float4*)&Qs[row][SWQ(row,cq)<<2] = v;
    }
  }

  float oc[4][4]={};
  float m_r[4], l_r[4];
  #pragma unroll
  for (int u=0;u<4;u++){ m_r[u] = -1e30f; l_r[u] = 0.f; }

  for (int kb=0; kb<NT; kb++){
    __syncthreads();
    const size_t kvb = (NT==1) ? (size_t)s*8192 : ((size_t)kb*4096 + t)*128;
    const int kvrs = (NT==1) ? 128 : 8192;
    #pragma unroll
    for (int it=0; it<4; it++){
      int f4 = it*256+tid; int row=f4>>4; int cq=f4&15;
      *(float4*)&Ks[row][SWQ(row,cq)<<2] = ld4f(Kc + kvb + (size_t)row*kvrs + ccol + (cq<<2));
      *(float4*)&Vs[row][SWQ(row,cq)<<2] = ld4f(Vc + kvb + (size_t)row*kvrs + ccol + (cq<<2));
    }
    __syncthreads();
    float sc[4][4]={};
    #pragma unroll 4
    for (int dq=0;dq<16;dq++){
      float4 qv[4], kv[4];
      #pragma unroll
      for (int u=0;u<4;u++) qv[u] = *(float4*)&Qs[i0+u][SWQ(i0+u,dq)<<2];
      #pragma unroll
      for (int w=0;w<4;w++) kv[w] = *(float4*)&Ks[j0+w][SWQ(j0+w,dq)<<2];
      #pragma unroll
      for (int u=0;u<4;u++)
        #pragma unroll
        for (int w=0;w<4;w++)
          sc[u][w] += qv[u].x*kv[w].x + qv[u].y*kv[w].y
                    + qv[u].z*kv[w].z + qv[u].w*kv[w].w;
    }
    __syncthreads();   // Ks score-reads done before P overwrite
    #pragma unroll
    for (int u=0;u<4;u++){
      float mx = fmaxf(fmaxf(sc[u][0],sc[u][1]),fmaxf(sc[u][2],sc[u][3]));
      #pragma unroll
      for (int msk=1; msk<16; msk<<=1) mx = fmaxf(mx, __shfl_xor(mx, msk));
      float mn = fmaxf(m_r[u], mx);
      float p[4]; float ps=0.f;
      #pragma unroll
      for (int w=0;w<4;w++){ p[w] = __expf(sc[u][w]-mn); ps += p[w]; }
      #pragma unroll
      for (int msk=1; msk<16; msk<<=1) ps += __shfl_xor(ps, msk);
      float sca = __expf(m_r[u]-mn);
      m_r[u] = mn;
      l_r[u] = l_r[u]*sca + ps;
      oc[u][0]*=sca; oc[u][1]*=sca; oc[u][2]*=sca; oc[u][3]*=sca;
      *(float4*)&Ks[i0+u][SWQ(i0+u,tx)<<2] = make_float4(p[0],p[1],p[2],p[3]);
    }
    __syncthreads();
    #pragma unroll 4
    for (int jq=0;jq<16;jq++){
      float4 pv4[4], vv[4];
      #pragma unroll
      for (int u=0;u<4;u++) pv4[u] = *(float4*)&Ks[i0+u][SWQ(i0+u,jq)<<2];
      #pragma unroll
      for (int q=0;q<4;q++) vv[q] = *(float4*)&Vs[(jq<<2)+q][SWQ((jq<<2)+q,tx)<<2];
      #pragma unroll
      for (int u=0;u<4;u++){
        float pa[4]={pv4[u].x,pv4[u].y,pv4[u].z,pv4[u].w};
        #pragma unroll
        for (int q=0;q<4;q++){
          oc[u][0] += pa[q]*vv[q].x; oc[u][1] += pa[q]*vv[q].y;
          oc[u][2] += pa[q]*vv[q].z; oc[u][3] += pa[q]*vv[q].w;
        }
      }
    }
  }
  #pragma unroll
  for (int u=0;u<4;u++){
    float inv = 1.0f/(l_r[u]*8.0f);
    size_t ga = qbase + (size_t)(i0+u)*qrs + gcol + j0;
    float4 r4 = ld4f(Resid + ga);
    st4f(O + ga, make_float4(oc[u][0]*inv+r4.x, oc[u][1]*inv+r4.y,
                             oc[u][2]*inv+r4.z, oc[u][3]*inv+r4.w));
  }
}

// ---------------------------------------------------------------- fused LN + FFN + residual (in-place ok)
template<typename T>
__global__ __launch_bounds__(256) void k_ffn(
    const T* X, T* Out,
    const float* __restrict__ lng, const float* __restrict__ lnb,
    const float* __restrict__ W1, const float* __restrict__ b1,
    const float* __restrict__ W2, const float* __restrict__ b2){
  __shared__ float Xs[32][260];
  __shared__ float H1s[32][68];
  const int tid = threadIdx.x;
  const int r0 = blockIdx.x<<5;
  #pragma unroll
  for (int i=0;i<8;i++){
    int f4 = i*256+tid; int row=f4>>6; int c4=(f4&63)<<2;
    *(float4*)&Xs[row][c4] = ld4f(X + (size_t)(r0+row)*256 + c4);
  }
  __syncthreads();
  {
    const int wv = tid>>6, lane = tid&63;
    for (int r=wv*8; r<wv*8+8; r++){
      float4 v = *(float4*)&Xs[r][lane<<2];
      float sm = wave_sum(v.x+v.y+v.z+v.w);
      float sq = wave_sum(v.x*v.x+v.y*v.y+v.z*v.z+v.w*v.w);
      float mean = sm*(1.f/256.f);
      float rs = rsqrtf(sq*(1.f/256.f) - mean*mean + 1e-10f);
      float4 gg = *(const float4*)(lng + (lane<<2));
      float4 bb = *(const float4*)(lnb + (lane<<2));
      v.x=(v.x-mean)*rs*gg.x+bb.x; v.y=(v.y-mean)*rs*gg.y+bb.y;
      v.z=(v.z-mean)*rs*gg.z+bb.z; v.w=(v.w-mean)*rs*gg.w+bb.w;
      *(float4*)&Xs[r][lane<<2] = v;
    }
  }
  __syncthreads();
  const int hn4 = (tid&15)<<2;
  const int hr0 = (tid>>4)<<1;
  const int ncol = (tid&63)<<2;
  const int rbase = (tid>>6)<<3;
  float acc[8][4] = {};
  for (int hc=0; hc<16; hc++){
    float h0[4]={0,0,0,0}, h1[4]={0,0,0,0};
    #pragma unroll 2
    for (int e=0;e<256;e++){
      float4 w = *(const float4*)(W1 + (size_t)e*1024 + (hc<<6) + hn4);
      float x0 = Xs[hr0][e], x1 = Xs[hr0+1][e];
      h0[0]+=x0*w.x; h0[1]+=x0*w.y; h0[2]+=x0*w.z; h0[3]+=x0*w.w;
      h1[0]+=x1*w.x; h1[1]+=x1*w.y; h1[2]+=x1*w.z; h1[3]+=x1*w.w;
    }
    float4 bb = *(const float4*)(b1 + (hc<<6) + hn4);
    *(float4*)&H1s[hr0][hn4] = make_float4(
      fmaxf(h0[0]+bb.x,0.f), fmaxf(h0[1]+bb.y,0.f),
      fmaxf(h0[2]+bb.z,0.f), fmaxf(h0[3]+bb.w,0.f));
    *(float4*)&H1s[hr0+1][hn4] = make_float4(
      fmaxf(h1[0]+bb.x,0.f), fmaxf(h1[1]+bb.y,0.f),
      fmaxf(h1[2]+bb.z,0.f), fmaxf(h1[3]+bb.w,0.f));
    __syncthreads();
    #pragma unroll 2
    for (int j=0;j<64;j++){
      float4 w2 = *(const float4*)(W2 + (size_t)((hc<<6)+j)*256 + ncol);
      #pragma unroll
      for (int r=0;r<8;r++){
        float p = H1s[rbase+r][j];
        acc[r][0]+=p*w2.x; acc[r][1]+=p*w2.y;
        acc[r][2]+=p*w2.z; acc[r][3]+=p*w2.w;
      }
    }
    __syncthreads();
  }
  float4 b2v = *(const float4*)(b2 + ncol);
  #pragma unroll
  for (int r=0;r<8;r++){
    size_t row = (size_t)r0 + rbase + r;
    float4 res = ld4f(X + row*256 + ncol);
    st4f(Out + row*256 + ncol,
      make_float4(acc[r][0]+b2v.x+res.x, acc[r][1]+b2v.y+res.y,
                  acc[r][2]+b2v.z+res.z, acc[r][3]+b2v.w+res.w));
  }
}

// ---------------------------------------------------------------- final head
template<typename T>
__global__ __launch_bounds__(256) void k_final2(const T* __restrict__ IO,
    const T* __restrict__ X1, const float* __restrict__ predW,
    const float* __restrict__ predb, float* __restrict__ out){
  const int s = blockIdx.x, tid = threadIdx.x;
  __shared__ float cur[256];
  __shared__ float lam[64];
  __shared__ float red[4];
  const int wv = tid>>6, lane = tid&63;
  cur[tid] = ld1(X1 + ((size_t)(s*64+63))*256 + tid);
  __syncthreads();
  float lg[16];
  for (int r=0;r<16;r++){
    int trow = wv*16+r;
    float4 xa = ld4f(X1 + ((size_t)(s*64+trow))*256 + (lane<<2));
    float4 xc = *(float4*)&cur[lane<<2];
    lg[r] = wave_sum(xa.x*xc.x + xa.y*xc.y + xa.z*xc.z + xa.w*xc.w);
  }
  if (lane==0){
    #pragma unroll
    for (int r=0;r<16;r++) lam[wv*16+r] = lg[r];
  }
  __syncthreads();
  if (tid < 64){
    float v = lam[tid];
    float mx = wave_max(v);
    float p = __expf(v-mx);
    float sm = wave_sum(p);
    lam[tid] = p/sm;
  }
  __syncthreads();
  float ag = 0.f;
  for (int tt=0;tt<64;tt++)
    ag += lam[tt]*ld1(IO + ((size_t)(s*64+tt))*256 + tid);
  float wsum = wave_sum(ag * predW[tid]);
  if (lane==0) red[wv] = wsum;
  __syncthreads();
  if (tid==0) out[s] = red[0]+red[1]+red[2]+red[3] + predb[0];
}

// ================================================================ pipeline
template<typename T>
static void run_pipeline(void* const* d_in, float* out, void* d_ws, hipStream_t stream){
  const float* x       = (const float*)d_in[0];
  const float* gate_W  = (const float*)d_in[1];
  const float* gate_b  = (const float*)d_in[2];
  const float* embed_W = (const float*)d_in[3];
  const float* ln0_g   = (const float*)d_in[4];
  const float* ln0_b   = (const float*)d_in[5];
  const float* iln_g   = (const float*)d_in[9];
  const float* iln_b   = (const float*)d_in[10];
  const float* iW1     = (const float*)d_in[11];
  const float* ib1     = (const float*)d_in[12];
  const float* iW2     = (const float*)d_in[13];
  const float* ib2     = (const float*)d_in[14];
  const float* eln1_g  = (const float*)d_in[18];
  const float* eln1_b  = (const float*)d_in[19];
  const float* eln2_g  = (const float*)d_in[20];
  const float* eln2_b  = (const float*)d_in[21];
  const float* eW1     = (const float*)d_in[22];
  const float* eb1     = (const float*)d_in[23];
  const float* eW2     = (const float*)d_in[24];
  const float* eb2     = (const float*)d_in[25];
  const float* temp_W  = (const float*)d_in[26];
  const float* pred_W  = (const float*)d_in[27];
  const float* pred_b  = (const float*)d_in[28];

  float* pe    = (float*)d_ws;          // 16384
  float* gate  = pe + 16384;            // 131072
  float* packW = gate + 131072;         // 6*65536
  char*  big   = (char*)d_ws + ((size_t)4<<20);
  const size_t MR = (size_t)65536*256, MH = (size_t)65536*128;
  T* A  = (T*)big;
  T* Bb = A  + MR;
  T* Cc = Bb + MR;
  T* Dd = Cc + MH;
  const float* pQ1 = packW, *pK1 = packW+65536, *pV1 = packW+131072;
  const float* pQ2 = packW+196608, *pK2 = packW+262144, *pV2 = packW+327680;

  k_pe  <<<64,  256, 0, stream>>>(pe);
  k_gate<<<1024, 64, 0, stream>>>(x, gate_W, gate_b, gate);
  k_pack<<<1536,256, 0, stream>>>((const float*)d_in[6],(const float*)d_in[7],
      (const float*)d_in[8],(const float*)d_in[15],(const float*)d_in[16],
      (const float*)d_in[17], packW);

  // A = (gate*x_f)@embed_W + pe ; LN0 in-place
  k_gemm<float,T,128,1><<<dim3(1024,4),256,0,stream>>>(x,192, embed_W,256, A,256, pe, gate);
  k_ln<T,T><<<16384,256,0,stream>>>(A, A, ln0_g, ln0_b);

  // intra attention, head-pair split; r -> B
  for (int hp=0; hp<2; hp++){
    int hb = hp*2;
    k_gemm<T,T,256,0><<<dim3(1024,2),256,0,stream>>>(A,256, pQ1+hb*64,256, Bb+hb*64,256, nullptr,nullptr);
    k_gemm<T,T,256,0><<<dim3(1024,2),256,0,stream>>>(A,256, pK1+hb*64,256, Cc,128, nullptr,nullptr);
    k_gemm<T,T,256,0><<<dim3(1024,2),256,0,stream>>>(A,256, pV1+hb*64,256, Dd,128, nullptr,nullptr);
    k_attn<T,1,false><<<dim3(1024,2),256,0,stream>>>(Bb, Cc, Dd, A, Bb, nullptr, hb);
  }
  k_ffn<T><<<2048,256,0,stream>>>(Bb, Bb, iln_g, iln_b, iW1, ib1, iW2, ib2);  // B = intra_out

  // inter attention (transposed batching), fused Q; r2 accumulated into B
  k_ln<T,T><<<16384,256,0,stream>>>(Bb, A, eln1_g, eln1_b);                   // A = ln1
  for (int hp=0; hp<2; hp++){
    int hb = hp*2;
    k_gemm<T,T,256,0><<<dim3(1024,2),256,0,stream>>>(A,256, pK2+hb*64,256, Cc,128, nullptr,nullptr);
    k_gemm<T,T,256,0><<<dim3(1024,2),256,0,stream>>>(A,256, pV2+hb*64,256, Dd,128, nullptr,nullptr);
    k_attn<T,16,true><<<dim3(2,64,16),256,0,stream>>>(A, Cc, Dd, Bb, Bb, pQ2, hb);
  }
  k_ffn<T><<<2048,256,0,stream>>>(Bb, Bb, eln2_g, eln2_b, eW1, eb1, eW2, eb2); // B = inter_out

  // head
  k_gemm<T,T,256,0><<<dim3(1024,4),256,0,stream>>>(Bb,256, temp_W,256, A,256, nullptr,nullptr);
  k_final2<T><<<1024,256,0,stream>>>(Bb, A, pred_W, pred_b, out);
}

extern "C" void kernel_launch(void* const* d_in, const int* in_sizes, int n_in,
                              void* d_out, int out_size, void* d_ws, size_t ws_size,
                              hipStream_t stream){
  float* out = (float*)d_out;
  const size_t need_f32 = ((size_t)4<<20) + (size_t)65536*256*4*2 + (size_t)65536*128*4*2; // 196 MiB
  if (ws_size >= need_f32)
    run_pipeline<float>(d_in, out, d_ws, stream);
  else
    run_pipeline<hb>(d_in, out, d_ws, stream);
}

// Round 3
// 2453.811 us; speedup vs baseline: 2.8414x; 2.8414x over previous
//
#include <hip/hip_runtime.h>

// S=1024, T=64, F=128, J=64, E=256, H=4, DH=64. M = S*T = 65536 rows.
// Storage T = float (default) or bf16-in-ushort (small-ws fallback).
// FFN uses f16 MFMA (v_mfma_f32_16x16x32_f16), fp32 accumulate.

typedef unsigned short hb;   // bf16 storage
typedef _Float16 h16;        // f16 storage for MFMA operands
typedef __attribute__((ext_vector_type(8))) _Float16 f16x8;
typedef __attribute__((ext_vector_type(4))) _Float16 f16x4;
typedef __attribute__((ext_vector_type(4))) float f32x4;

__device__ inline float b2f(hb u){ return __uint_as_float(((unsigned)u)<<16); }
__device__ inline hb f2b(float x){
  unsigned a = __float_as_uint(x);
  return (hb)((a + 0x7fffu + ((a>>16)&1u)) >> 16);
}
__device__ inline float4 ld4f(const float* p){ return *(const float4*)p; }
__device__ inline float4 ld4f(const hb* p){
  ushort4 u = *(const ushort4*)p;
  return make_float4(b2f(u.x), b2f(u.y), b2f(u.z), b2f(u.w));
}
__device__ inline void st4f(float* p, float4 v){ *(float4*)p = v; }
__device__ inline void st4f(hb* p, float4 v){
  ushort4 u; u.x=f2b(v.x); u.y=f2b(v.y); u.z=f2b(v.z); u.w=f2b(v.w);
  *(ushort4*)p = u;
}
__device__ inline float ld1(const float* p){ return *p; }
__device__ inline float ld1(const hb* p){ return b2f(*p); }
__device__ inline void st1(float* p, float v){ *p = v; }
__device__ inline void st1(hb* p, float v){ *p = f2b(v); }

__device__ inline float wave_sum(float v){
  #pragma unroll
  for (int o=32;o;o>>=1) v += __shfl_xor(v,o);
  return v;
}
__device__ inline float wave_max(float v){
  #pragma unroll
  for (int o=32;o;o>>=1) v = fmaxf(v,__shfl_xor(v,o));
  return v;
}

// ---------------------------------------------------------------- pe table
__global__ __launch_bounds__(256) void k_pe(float* __restrict__ pe){
  int t = blockIdx.x, i = threadIdx.x;
  float two_i = (float)((i>>1)<<1);
  float dv = powf(100004.0f, two_i*(1.0f/256.0f));
  float v = (float)t / dv;
  pe[t*256+i] = (i&1) ? cosf(v) : sinf(v);
}

// ---------------------------------------------------------------- gate softmax
__global__ __launch_bounds__(64) void k_gate(const float* __restrict__ x,
    const float* __restrict__ gW, const float* __restrict__ gb,
    float* __restrict__ gate){
  int s = blockIdx.x, lane = threadIdx.x;
  __shared__ float xg[64];
  xg[lane] = x[((size_t)s*64+63)*192 + 128 + lane];
  __syncthreads();
  float a0 = gb[lane], a1 = gb[64+lane];
  #pragma unroll 4
  for (int j=0;j<64;j++){
    float xv = xg[j];
    a0 += xv*gW[j*128+lane];
    a1 += xv*gW[j*128+64+lane];
  }
  float mx = wave_max(fmaxf(a0,a1));
  float e0 = __expf(a0-mx), e1 = __expf(a1-mx);
  float sm = wave_sum(e0+e1);
  gate[s*128+lane]    = e0/sm;
  gate[s*128+64+lane] = e1/sm;
}

// ---------------------------------------------------------------- pack (H,E,DH) -> (E, H*DH)
__global__ __launch_bounds__(256) void k_pack(const float* __restrict__ w0,
    const float* __restrict__ w1, const float* __restrict__ w2,
    const float* __restrict__ w3, const float* __restrict__ w4,
    const float* __restrict__ w5, float* __restrict__ pack){
  int g = blockIdx.x*256 + threadIdx.x;
  int mat = g>>16; int local = g&65535;
  int e = local>>8; int n = local&255;
  const float* src = (mat==0)?w0:(mat==1)?w1:(mat==2)?w2:(mat==3)?w3:(mat==4)?w4:w5;
  pack[g] = src[((n>>6)<<14) + (e<<6) + (n&63)];
}

// ---------------------------------------------------------------- FFN weight transpose+convert
// W1 [256x1024] -> W1t f16 [n=1024][k=256]; W2 [1024x256] -> W2t f16 [n=256][k=1024]
// grid 1024: block = one 32x32 tile. b: layer = b>>9, mat = (b>>8)&1, t = b&255.
__global__ __launch_bounds__(256) void k_transpose(
    const float* __restrict__ iW1, const float* __restrict__ iW2,
    const float* __restrict__ eW1, const float* __restrict__ eW2,
    h16* __restrict__ fW){
  __shared__ float tile[32][33];
  const int b = blockIdx.x, tid = threadIdx.x;
  const int layer = b>>9, mat = (b>>8)&1, t = b&255;
  const float* src = layer ? (mat ? eW2 : eW1) : (mat ? iW2 : iW1);
  h16* dst = fW + layer*524288 + mat*262144;
  const int ldsrc = mat ? 256 : 1024;   // src row length (n-dim)
  const int lddst = mat ? 1024 : 256;   // dst row length (k-dim)
  int tr, tc;
  if (mat==0){ tr = t>>5; tc = t&31; }  // W1: 8 x 32 tiles
  else       { tr = t>>3; tc = t&7;  }  // W2: 32 x 8 tiles
  const int R0 = tr<<5, C0 = tc<<5;     // R=k, C=n
  {
    int row = tid>>3, c0 = (tid&7)<<2;
    float4 v = *(const float4*)(src + (size_t)(R0+row)*ldsrc + C0 + c0);
    tile[row][c0]=v.x; tile[row][c0+1]=v.y; tile[row][c0+2]=v.z; tile[row][c0+3]=v.w;
  }
  __syncthreads();
  {
    int row = tid>>3, c0 = (tid&7)<<2;  // row = n-local, c0 = k-local
    f16x4 o;
    o[0]=(h16)tile[c0][row]; o[1]=(h16)tile[c0+1][row];
    o[2]=(h16)tile[c0+2][row]; o[3]=(h16)tile[c0+3][row];
    *(f16x4*)(dst + (size_t)(C0+row)*lddst + R0 + c0) = o;
  }
}

// ---------------------------------------------------------------- generic GEMM (fp32 VALU)
template<typename TI, typename TO, int KDIM, int MODE>
__global__ __launch_bounds__(256) void k_gemm(
    const TI* __restrict__ A, int lda,
    const float* __restrict__ Bm, int ldb,
    TO* __restrict__ Cm, int ldc,
    const float* __restrict__ pe, const float* __restrict__ gate){
  __shared__ float As[32][68];
  __shared__ float Bs[32][68];
  const int tid = threadIdx.x;
  const int m0 = blockIdx.x<<6, n0 = blockIdx.y<<6;
  const int tx = tid&15, ty = tid>>4;
  float acc[4][4] = {};
  for (int k0=0; k0<KDIM; k0+=32){
    #pragma unroll
    for (int i=0;i<2;i++){
      int id = tid*2+i;
      int row = id>>3, kq = id&7;
      float4 v = ld4f(A + (size_t)(m0+row)*lda + k0 + (kq<<2));
      if (MODE==1){
        const float* gp = gate + (((m0+row)>>6)<<7) + k0 + (kq<<2);
        float4 gg = *(const float4*)gp;
        v.x*=gg.x; v.y*=gg.y; v.z*=gg.z; v.w*=gg.w;
      }
      As[(kq<<2)+0][row]=v.x; As[(kq<<2)+1][row]=v.y;
      As[(kq<<2)+2][row]=v.z; As[(kq<<2)+3][row]=v.w;
      int brow = id>>4, bq = id&15;
      *(float4*)&Bs[brow][bq<<2] =
        *(const float4*)(Bm + (size_t)(k0+brow)*ldb + n0 + (bq<<2));
    }
    __syncthreads();
    #pragma unroll
    for (int kk=0;kk<32;kk++){
      float4 a4 = *(float4*)&As[kk][ty<<2];
      float4 b4 = *(float4*)&Bs[kk][tx<<2];
      float av[4]={a4.x,a4.y,a4.z,a4.w};
      float bv[4]={b4.x,b4.y,b4.z,b4.w};
      #pragma unroll
      for (int u=0;u<4;u++)
        #pragma unroll
        for (int w=0;w<4;w++) acc[u][w] += av[u]*bv[w];
    }
    __syncthreads();
  }
  #pragma unroll
  for (int u=0;u<4;u++){
    int row = m0 + (ty<<2) + u;
    float4 o = make_float4(acc[u][0],acc[u][1],acc[u][2],acc[u][3]);
    if (MODE==1){
      float4 p4 = *(const float4*)(pe + ((row&63)<<8) + n0 + (tx<<2));
      o.x+=p4.x; o.y+=p4.y; o.z+=p4.z; o.w+=p4.w;
    }
    st4f(Cm + (size_t)row*ldc + n0 + (tx<<2), o);
  }
}

// ---------------------------------------------------------------- row LayerNorm
template<typename TI, typename TO>
__global__ __launch_bounds__(256) void k_ln(const TI* __restrict__ in,
    TO* __restrict__ out, const float* __restrict__ g,
    const float* __restrict__ b){
  const int wv = threadIdx.x>>6, lane = threadIdx.x&63;
  const size_t row = (size_t)blockIdx.x*4 + wv;
  float4 v = ld4f(in + row*256 + (lane<<2));
  float sm = wave_sum(v.x+v.y+v.z+v.w);
  float sq = wave_sum(v.x*v.x+v.y*v.y+v.z*v.z+v.w*v.w);
  float mean = sm*(1.f/256.f);
  float rs = rsqrtf(sq*(1.f/256.f) - mean*mean + 1e-10f);
  float4 gg = *(const float4*)(g + (lane<<2));
  float4 bb = *(const float4*)(b + (lane<<2));
  float4 o;
  o.x=(v.x-mean)*rs*gg.x+bb.x; o.y=(v.y-mean)*rs*gg.y+bb.y;
  o.z=(v.z-mean)*rs*gg.z+bb.z; o.w=(v.w-mean)*rs*gg.w+bb.w;
  st4f(out + row*256 + (lane<<2), o);
}

// LDS quad-index XOR swizzle (fp32 attention tiles)
#define SWQ(row, dq) (((dq) ^ (((row)>>2)&7)))
__device__ inline float xc_read(const float (*Xc)[64], int row, int kk){
  return Xc[row][((((kk)>>2) ^ (((row)>>2)&7))<<2) | ((kk)&3)];
}

// ---------------------------------------------------------------- unified attention (fp32)
template<typename T, int NT, bool FUSEQ>
__global__ __launch_bounds__(256) void k_attn(
    const T* __restrict__ Xq, const T* __restrict__ Kc, const T* __restrict__ Vc,
    const T* Resid, T* O, const float* __restrict__ Wq, int hbase){
  __shared__ float Qs[64][64], Ks[64][64], Vs[64][64];
  const int tid = threadIdx.x;
  int hh, t=0, qc=0, s=0;
  if (NT==1){ s = blockIdx.x; hh = blockIdx.y; }
  else      { hh = blockIdx.x; t = blockIdx.y; qc = blockIdx.z; }
  const int gcol = (hbase+hh)<<6;
  const int ccol = hh<<6;
  const size_t qbase = (NT==1) ? (size_t)s*16384 : ((size_t)qc*4096 + t)*256;
  const int qrs = (NT==1) ? 256 : 16384;
  const int i0 = (tid>>4)<<2;
  const int j0 = (tid&15)<<2;
  const int tx = tid&15;

  if (FUSEQ){
    float qa[4][4] = {};
    for (int kc=0; kc<4; kc++){
      #pragma unroll
      for (int it=0; it<4; it++){
        int f4 = it*256+tid; int row=f4>>4; int cq=f4&15;
        float4 v = ld4f(Xq + qbase + (size_t)row*qrs + (kc<<6) + (cq<<2));
        *(float4*)&Ks[row][SWQ(row,cq)<<2] = v;
        *(float4*)&Vs[row][cq<<2] =
          *(const float4*)(Wq + (size_t)((kc<<6)+row)*256 + gcol + (cq<<2));
      }
      __syncthreads();
      for (int kk=0;kk<64;kk++){
        float4 w4 = *(float4*)&Vs[kk][j0];
        #pragma unroll
        for (int u=0;u<4;u++){
          float xv = xc_read(Ks, i0+u, kk);
          qa[u][0]+=xv*w4.x; qa[u][1]+=xv*w4.y;
          qa[u][2]+=xv*w4.z; qa[u][3]+=xv*w4.w;
        }
      }
      __syncthreads();
    }
    #pragma unroll
    for (int u=0;u<4;u++)
      *(float4*)&Qs[i0+u][SWQ(i0+u,tx)<<2] =
        make_float4(qa[u][0],qa[u][1],qa[u][2],qa[u][3]);
  } else {
    #pragma unroll
    for (int it=0; it<4; it++){
      int f4 = it*256+tid; int row=f4>>4; int cq=f4&15;
      float4 v = ld4f(Xq + qbase + (size_t)row*qrs + gcol + (cq<<2));
      *(float4*)&Qs[row][SWQ(row,cq)<<2] = v;
    }
  }

  float oc[4][4]={};
  float m_r[4], l_r[4];
  #pragma unroll
  for (int u=0;u<4;u++){ m_r[u] = -1e30f; l_r[u] = 0.f; }

  for (int kb=0; kb<NT; kb++){
    __syncthreads();
    const size_t kvb = (NT==1) ? (size_t)s*8192 : ((size_t)kb*4096 + t)*128;
    const int kvrs = (NT==1) ? 128 : 8192;
    #pragma unroll
    for (int it=0; it<4; it++){
      int f4 = it*256+tid; int row=f4>>4; int cq=f4&15;
      *(float4*)&Ks[row][SWQ(row,cq)<<2] = ld4f(Kc + kvb + (size_t)row*kvrs + ccol + (cq<<2));
      *(float4*)&Vs[row][SWQ(row,cq)<<2] = ld4f(Vc + kvb + (size_t)row*kvrs + ccol + (cq<<2));
    }
    __syncthreads();
    float sc[4][4]={};
    #pragma unroll 4
    for (int dq=0;dq<16;dq++){
      float4 qv[4], kv[4];
      #pragma unroll
      for (int u=0;u<4;u++) qv[u] = *(float4*)&Qs[i0+u][SWQ(i0+u,dq)<<2];
      #pragma unroll
      for (int w=0;w<4;w++) kv[w] = *(float4*)&Ks[j0+w][SWQ(j0+w,dq)<<2];
      #pragma unroll
      for (int u=0;u<4;u++)
        #pragma unroll
        for (int w=0;w<4;w++)
          sc[u][w] += qv[u].x*kv[w].x + qv[u].y*kv[w].y
                    + qv[u].z*kv[w].z + qv[u].w*kv[w].w;
    }
    __syncthreads();
    #pragma unroll
    for (int u=0;u<4;u++){
      float mx = fmaxf(fmaxf(sc[u][0],sc[u][1]),fmaxf(sc[u][2],sc[u][3]));
      #pragma unroll
      for (int msk=1; msk<16; msk<<=1) mx = fmaxf(mx, __shfl_xor(mx, msk));
      float mn = fmaxf(m_r[u], mx);
      float p[4]; float ps=0.f;
      #pragma unroll
      for (int w=0;w<4;w++){ p[w] = __expf(sc[u][w]-mn); ps += p[w]; }
      #pragma unroll
      for (int msk=1; msk<16; msk<<=1) ps += __shfl_xor(ps, msk);
      float sca = __expf(m_r[u]-mn);
      m_r[u] = mn;
      l_r[u] = l_r[u]*sca + ps;
      oc[u][0]*=sca; oc[u][1]*=sca; oc[u][2]*=sca; oc[u][3]*=sca;
      *(float4*)&Ks[i0+u][SWQ(i0+u,tx)<<2] = make_float4(p[0],p[1],p[2],p[3]);
    }
    __syncthreads();
    #pragma unroll 4
    for (int jq=0;jq<16;jq++){
      float4 pv4[4], vv[4];
      #pragma unroll
      for (int u=0;u<4;u++) pv4[u] = *(float4*)&Ks[i0+u][SWQ(i0+u,jq)<<2];
      #pragma unroll
      for (int q=0;q<4;q++) vv[q] = *(float4*)&Vs[(jq<<2)+q][SWQ((jq<<2)+q,tx)<<2];
      #pragma unroll
      for (int u=0;u<4;u++){
        float pa[4]={pv4[u].x,pv4[u].y,pv4[u].z,pv4[u].w};
        #pragma unroll
        for (int q=0;q<4;q++){
          oc[u][0] += pa[q]*vv[q].x; oc[u][1] += pa[q]*vv[q].y;
          oc[u][2] += pa[q]*vv[q].z; oc[u][3] += pa[q]*vv[q].w;
        }
      }
    }
  }
  #pragma unroll
  for (int u=0;u<4;u++){
    float inv = 1.0f/(l_r[u]*8.0f);
    size_t ga = qbase + (size_t)(i0+u)*qrs + gcol + j0;
    float4 r4 = ld4f(Resid + ga);
    st4f(O + ga, make_float4(oc[u][0]*inv+r4.x, oc[u][1]*inv+r4.y,
                             oc[u][2]*inv+r4.z, oc[u][3]*inv+r4.w));
  }
}

// ---------------------------------------------------------------- MFMA FFN
// Out = X + relu(LN(X)@W1+b1)@W2 + b2. Block: 64 rows, 4 waves; wave w owns
// output cols [w*64,(w+1)*64). Hidden in 4 chunks of 256. f16 operands,
// fp32 accum. LDS tiles XOR-swizzled on 16B units: idx ^= (row&7)<<3 (h16 units).
template<typename T>
__global__ __launch_bounds__(256) void k_ffn_mfma(
    const T* X, T* Out,
    const float* __restrict__ lng, const float* __restrict__ lnb,
    const h16* __restrict__ W1t, const float* __restrict__ b1,
    const h16* __restrict__ W2t, const float* __restrict__ b2){
  __shared__ h16 Xs[64*256];   // 32 KB, LN'd A-tile [r][k]
  __shared__ h16 Hc[64*256];   // 32 KB, hidden chunk [r][j]
  const int tid  = threadIdx.x;
  const int lane = tid & 63;
  const int w    = tid >> 6;    // wave id 0..3
  const int r0   = blockIdx.x << 6;
  const int lr   = lane & 15;   // A-row / B-col within frag
  const int lg   = lane >> 4;   // k-group

  // ---- LN phase: wave w rows [w*16, w*16+16)
  {
    float4 gg = *(const float4*)(lng + (lane<<2));
    float4 bb = *(const float4*)(lnb + (lane<<2));
    for (int rr=0; rr<16; rr++){
      int r = (w<<4) + rr;
      float4 v = ld4f(X + (size_t)(r0+r)*256 + (lane<<2));
      float sm = wave_sum(v.x+v.y+v.z+v.w);
      float sq = wave_sum(v.x*v.x+v.y*v.y+v.z*v.z+v.w*v.w);
      float mean = sm*(1.f/256.f);
      float rs = rsqrtf(sq*(1.f/256.f) - mean*mean + 1e-10f);
      f16x4 o;
      o[0]=(h16)((v.x-mean)*rs*gg.x+bb.x); o[1]=(h16)((v.y-mean)*rs*gg.y+bb.y);
      o[2]=(h16)((v.z-mean)*rs*gg.z+bb.z); o[3]=(h16)((v.w-mean)*rs*gg.w+bb.w);
      int idx = ((r<<8) + (lane<<2)) ^ ((r&7)<<3);
      *(f16x4*)&Xs[idx] = o;
    }
  }
  __syncthreads();

  f32x4 acc2[4][4];
  #pragma unroll
  for (int a=0;a<4;a++)
    #pragma unroll
    for (int b=0;b<4;b++) acc2[a][b] = (f32x4){0.f,0.f,0.f,0.f};

  for (int hc=0; hc<4; hc++){
    // GEMM1: acc1 = Xs @ W1t-chunk  (wave cols: hc*256 + w*64 + ...)
    f32x4 acc1[4][4];
    #pragma unroll
    for (int a=0;a<4;a++)
      #pragma unroll
      for (int b=0;b<4;b++) acc1[a][b] = (f32x4){0.f,0.f,0.f,0.f};
    #pragma unroll
    for (int kt=0; kt<8; kt++){
      f16x8 af[4], bf[4];
      #pragma unroll
      for (int rf=0; rf<4; rf++){
        int r = (rf<<4) + lr;
        int idx = ((r<<8) + (kt<<5) + (lg<<3)) ^ ((r&7)<<3);
        af[rf] = *(const f16x8*)&Xs[idx];
      }
      #pragma unroll
      for (int cf=0; cf<4; cf++){
        int n = (hc<<8) + (w<<6) + (cf<<4) + lr;
        bf[cf] = *(const f16x8*)(W1t + (size_t)n*256 + (kt<<5) + (lg<<3));
      }
      #pragma unroll
      for (int rf=0; rf<4; rf++)
        #pragma unroll
        for (int cf=0; cf<4; cf++)
          acc1[rf][cf] = __builtin_amdgcn_mfma_f32_16x16x32_f16(
              af[rf], bf[cf], acc1[rf][cf], 0, 0, 0);
    }
    __syncthreads();   // prior-chunk GEMM2 reads of Hc complete
    // bias + relu -> Hc (f16). C layout: col=lane&15, row=(lane>>4)*4+reg.
    #pragma unroll
    for (int cf=0; cf<4; cf++){
      int cl = (w<<6) + (cf<<4) + lr;       // local hidden col 0..255
      float bv = b1[(hc<<8) + cl];
      #pragma unroll
      for (int rf=0; rf<4; rf++){
        #pragma unroll
        for (int i=0;i<4;i++){
          int r = (rf<<4) + (lg<<2) + i;
          float hv = fmaxf(acc1[rf][cf][i] + bv, 0.f);
          int idx = ((r<<8) + cl) ^ ((r&7)<<3);
          Hc[idx] = (h16)hv;
        }
      }
    }
    __syncthreads();
    // GEMM2: acc2 += Hc @ W2t-chunk (K = this hidden chunk)
    #pragma unroll
    for (int kt=0; kt<8; kt++){
      f16x8 af[4], bf[4];
      #pragma unroll
      for (int rf=0; rf<4; rf++){
        int r = (rf<<4) + lr;
        int idx = ((r<<8) + (kt<<5) + (lg<<3)) ^ ((r&7)<<3);
        af[rf] = *(const f16x8*)&Hc[idx];
      }
      #pragma unroll
      for (int cf=0; cf<4; cf++){
        int n = (w<<6) + (cf<<4) + lr;
        bf[cf] = *(const f16x8*)(W2t + (size_t)n*1024 + (hc<<8) + (kt<<5) + (lg<<3));
      }
      #pragma unroll
      for (int rf=0; rf<4; rf++)
        #pragma unroll
        for (int cf=0; cf<4; cf++)
          acc2[rf][cf] = __builtin_amdgcn_mfma_f32_16x16x32_f16(
              af[rf], bf[cf], acc2[rf][cf], 0, 0, 0);
    }
  }
  // epilogue: + b2 + residual
  #pragma unroll
  for (int cf=0; cf<4; cf++){
    int col = (w<<6) + (cf<<4) + lr;
    float bv = b2[col];
    #pragma unroll
    for (int rf=0; rf<4; rf++){
      #pragma unroll
      for (int i=0;i<4;i++){
        size_t r = (size_t)r0 + (rf<<4) + (lg<<2) + i;
        float res = ld1(X + r*256 + col);
        st1(Out + r*256 + col, acc2[rf][cf][i] + bv + res);
      }
    }
  }
}

// ---------------------------------------------------------------- fp32 VALU FFN (fallback)
template<typename T>
__global__ __launch_bounds__(256) void k_ffn(
    const T* X, T* Out,
    const float* __restrict__ lng, const float* __restrict__ lnb,
    const float* __restrict__ W1, const float* __restrict__ b1,
    const float* __restrict__ W2, const float* __restrict__ b2){
  __shared__ float Xs[32][260];
  __shared__ float H1s[32][68];
  const int tid = threadIdx.x;
  const int r0 = blockIdx.x<<5;
  #pragma unroll
  for (int i=0;i<8;i++){
    int f4 = i*256+tid; int row=f4>>6; int c4=(f4&63)<<2;
    *(float4*)&Xs[row][c4] = ld4f(X + (size_t)(r0+row)*256 + c4);
  }
  __syncthreads();
  {
    const int wv = tid>>6, lane = tid&63;
    for (int r=wv*8; r<wv*8+8; r++){
      float4 v = *(float4*)&Xs[r][lane<<2];
      float sm = wave_sum(v.x+v.y+v.z+v.w);
      float sq = wave_sum(v.x*v.x+v.y*v.y+v.z*v.z+v.w*v.w);
      float mean = sm*(1.f/256.f);
      float rs = rsqrtf(sq*(1.f/256.f) - mean*mean + 1e-10f);
      float4 gg = *(const float4*)(lng + (lane<<2));
      float4 bb = *(const float4*)(lnb + (lane<<2));
      v.x=(v.x-mean)*rs*gg.x+bb.x; v.y=(v.y-mean)*rs*gg.y+bb.y;
      v.z=(v.z-mean)*rs*gg.z+bb.z; v.w=(v.w-mean)*rs*gg.w+bb.w;
      *(float4*)&Xs[r][lane<<2] = v;
    }
  }
  __syncthreads();
  const int hn4 = (tid&15)<<2;
  const int hr0 = (tid>>4)<<1;
  const int ncol = (tid&63)<<2;
  const int rbase = (tid>>6)<<3;
  float acc[8][4] = {};
  for (int hc=0; hc<16; hc++){
    float h0[4]={0,0,0,0}, h1[4]={0,0,0,0};
    #pragma unroll 2
    for (int e=0;e<256;e++){
      float4 w = *(const float4*)(W1 + (size_t)e*1024 + (hc<<6) + hn4);
      float x0 = Xs[hr0][e], x1 = Xs[hr0+1][e];
      h0[0]+=x0*w.x; h0[1]+=x0*w.y; h0[2]+=x0*w.z; h0[3]+=x0*w.w;
      h1[0]+=x1*w.x; h1[1]+=x1*w.y; h1[2]+=x1*w.z; h1[3]+=x1*w.w;
    }
    float4 bb = *(const float4*)(b1 + (hc<<6) + hn4);
    *(float4*)&H1s[hr0][hn4] = make_float4(
      fmaxf(h0[0]+bb.x,0.f), fmaxf(h0[1]+bb.y,0.f),
      fmaxf(h0[2]+bb.z,0.f), fmaxf(h0[3]+bb.w,0.f));
    *(float4*)&H1s[hr0+1][hn4] = make_float4(
      fmaxf(h1[0]+bb.x,0.f), fmaxf(h1[1]+bb.y,0.f),
      fmaxf(h1[2]+bb.z,0.f), fmaxf(h1[3]+bb.w,0.f));
    __syncthreads();
    #pragma unroll 2
    for (int j=0;j<64;j++){
      float4 w2 = *(const float4*)(W2 + (size_t)((hc<<6)+j)*256 + ncol);
      #pragma unroll
      for (int r=0;r<8;r++){
        float p = H1s[rbase+r][j];
        acc[r][0]+=p*w2.x; acc[r][1]+=p*w2.y;
        acc[r][2]+=p*w2.z; acc[r][3]+=p*w2.w;
      }
    }
    __syncthreads();
  }
  float4 b2v = *(const float4*)(b2 + ncol);
  #pragma unroll
  for (int r=0;r<8;r++){
    size_t row = (size_t)r0 + rbase + r;
    float4 res = ld4f(X + row*256 + ncol);
    st4f(Out + row*256 + ncol,
      make_float4(acc[r][0]+b2v.x+res.x, acc[r][1]+b2v.y+res.y,
                  acc[r][2]+b2v.z+res.z, acc[r][3]+b2v.w+res.w));
  }
}

// ---------------------------------------------------------------- final head
template<typename T>
__global__ __launch_bounds__(256) void k_final2(const T* __restrict__ IO,
    const T* __restrict__ X1, const float* __restrict__ predW,
    const float* __restrict__ predb, float* __restrict__ out){
  const int s = blockIdx.x, tid = threadIdx.x;
  __shared__ float cur[256];
  __shared__ float lam[64];
  __shared__ float red[4];
  const int wv = tid>>6, lane = tid&63;
  cur[tid] = ld1(X1 + ((size_t)(s*64+63))*256 + tid);
  __syncthreads();
  float lg[16];
  for (int r=0;r<16;r++){
    int trow = wv*16+r;
    float4 xa = ld4f(X1 + ((size_t)(s*64+trow))*256 + (lane<<2));
    float4 xc = *(float4*)&cur[lane<<2];
    lg[r] = wave_sum(xa.x*xc.x + xa.y*xc.y + xa.z*xc.z + xa.w*xc.w);
  }
  if (lane==0){
    #pragma unroll
    for (int r=0;r<16;r++) lam[wv*16+r] = lg[r];
  }
  __syncthreads();
  if (tid < 64){
    float v = lam[tid];
    float mx = wave_max(v);
    float p = __expf(v-mx);
    float sm = wave_sum(p);
    lam[tid] = p/sm;
  }
  __syncthreads();
  float ag = 0.f;
  for (int tt=0;tt<64;tt++)
    ag += lam[tt]*ld1(IO + ((size_t)(s*64+tt))*256 + tid);
  float wsum = wave_sum(ag * predW[tid]);
  if (lane==0) red[wv] = wsum;
  __syncthreads();
  if (tid==0) out[s] = red[0]+red[1]+red[2]+red[3] + predb[0];
}

// ================================================================ pipeline
template<typename T>
static void run_pipeline(void* const* d_in, float* out, void* d_ws,
                         hipStream_t stream, bool mfma){
  const float* x       = (const float*)d_in[0];
  const float* gate_W  = (const float*)d_in[1];
  const float* gate_b  = (const float*)d_in[2];
  const float* embed_W = (const float*)d_in[3];
  const float* ln0_g   = (const float*)d_in[4];
  const float* ln0_b   = (const float*)d_in[5];
  const float* iln_g   = (const float*)d_in[9];
  const float* iln_b   = (const float*)d_in[10];
  const float* iW1     = (const float*)d_in[11];
  const float* ib1     = (const float*)d_in[12];
  const float* iW2     = (const float*)d_in[13];
  const float* ib2     = (const float*)d_in[14];
  const float* eln1_g  = (const float*)d_in[18];
  const float* eln1_b  = (const float*)d_in[19];
  const float* eln2_g  = (const float*)d_in[20];
  const float* eln2_b  = (const float*)d_in[21];
  const float* eW1     = (const float*)d_in[22];
  const float* eb1     = (const float*)d_in[23];
  const float* eW2     = (const float*)d_in[24];
  const float* eb2     = (const float*)d_in[25];
  const float* temp_W  = (const float*)d_in[26];
  const float* pred_W  = (const float*)d_in[27];
  const float* pred_b  = (const float*)d_in[28];

  float* pe    = (float*)d_ws;          // 16384 f
  float* gate  = pe + 16384;            // 131072 f
  float* packW = gate + 131072;         // 393216 f (QKV fp32)
  h16*   fW    = (h16*)((char*)d_ws + ((size_t)4<<20));   // 2 MiB f16 FFN weights
  char*  big   = (char*)d_ws + (mfma ? ((size_t)8<<20) : ((size_t)4<<20));
  const size_t MR = (size_t)65536*256, MH = (size_t)65536*128;
  T* A  = (T*)big;
  T* Bb = A  + MR;
  T* Cc = Bb + MR;
  T* Dd = Cc + MH;
  const float* pQ1 = packW, *pK1 = packW+65536, *pV1 = packW+131072;
  const float* pQ2 = packW+196608, *pK2 = packW+262144, *pV2 = packW+327680;

  k_pe  <<<64,  256, 0, stream>>>(pe);
  k_gate<<<1024, 64, 0, stream>>>(x, gate_W, gate_b, gate);
  k_pack<<<1536,256, 0, stream>>>((const float*)d_in[6],(const float*)d_in[7],
      (const float*)d_in[8],(const float*)d_in[15],(const float*)d_in[16],
      (const float*)d_in[17], packW);
  if (mfma)
    k_transpose<<<1024,256,0,stream>>>(iW1, iW2, eW1, eW2, fW);

  // A = (gate*x_f)@embed_W + pe ; LN0 in-place
  k_gemm<float,T,128,1><<<dim3(1024,4),256,0,stream>>>(x,192, embed_W,256, A,256, pe, gate);
  k_ln<T,T><<<16384,256,0,stream>>>(A, A, ln0_g, ln0_b);

  // intra attention, head-pair split; r -> B
  for (int hp=0; hp<2; hp++){
    int hb2 = hp*2;
    k_gemm<T,T,256,0><<<dim3(1024,2),256,0,stream>>>(A,256, pQ1+hb2*64,256, Bb+hb2*64,256, nullptr,nullptr);
    k_gemm<T,T,256,0><<<dim3(1024,2),256,0,stream>>>(A,256, pK1+hb2*64,256, Cc,128, nullptr,nullptr);
    k_gemm<T,T,256,0><<<dim3(1024,2),256,0,stream>>>(A,256, pV1+hb2*64,256, Dd,128, nullptr,nullptr);
    k_attn<T,1,false><<<dim3(1024,2),256,0,stream>>>(Bb, Cc, Dd, A, Bb, nullptr, hb2);
  }
  if (mfma)
    k_ffn_mfma<T><<<1024,256,0,stream>>>(Bb, Bb, iln_g, iln_b, fW, ib1, fW+262144, ib2);
  else
    k_ffn<T><<<2048,256,0,stream>>>(Bb, Bb, iln_g, iln_b, iW1, ib1, iW2, ib2);

  // inter attention (transposed batching), fused Q; r2 accumulated into B
  k_ln<T,T><<<16384,256,0,stream>>>(Bb, A, eln1_g, eln1_b);
  for (int hp=0; hp<2; hp++){
    int hb2 = hp*2;
    k_gemm<T,T,256,0><<<dim3(1024,2),256,0,stream>>>(A,256, pK2+hb2*64,256, Cc,128, nullptr,nullptr);
    k_gemm<T,T,256,0><<<dim3(1024,2),256,0,stream>>>(A,256, pV2+hb2*64,256, Dd,128, nullptr,nullptr);
    k_attn<T,16,true><<<dim3(2,64,16),256,0,stream>>>(A, Cc, Dd, Bb, Bb, pQ2, hb2);
  }
  if (mfma)
    k_ffn_mfma<T><<<1024,256,0,stream>>>(Bb, Bb, eln2_g, eln2_b, fW+524288, eb1, fW+786432, eb2);
  else
    k_ffn<T><<<2048,256,0,stream>>>(Bb, Bb, eln2_g, eln2_b, eW1, eb1, eW2, eb2);

  // head
  k_gemm<T,T,256,0><<<dim3(1024,4),256,0,stream>>>(Bb,256, temp_W,256, A,256, nullptr,nullptr);
  k_final2<T><<<1024,256,0,stream>>>(Bb, A, pred_W, pred_b, out);
}

extern "C" void kernel_launch(void* const* d_in, const int* in_sizes, int n_in,
                              void* d_out, int out_size, void* d_ws, size_t ws_size,
                              hipStream_t stream){
  float* out = (float*)d_out;
  const size_t MB = (size_t)1<<20;
  const size_t big_f32 = (size_t)65536*256*4*2 + (size_t)65536*128*4*2; // 192 MiB
  if (ws_size >= 8*MB + big_f32)
    run_pipeline<float>(d_in, out, d_ws, stream, true);
  else if (ws_size >= 4*MB + big_f32)
    run_pipeline<float>(d_in, out, d_ws, stream, false);
  else
    run_pipeline<hb>(d_in, out, d_ws, stream, false);
}

// Round 4
// 979.732 us; speedup vs baseline: 7.1166x; 2.5046x over previous
//
#include <hip/hip_runtime.h>

// S=1024, T=64, F=128, J=64, E=256, H=4, DH=64. M = S*T = 65536 rows.
// fp32 residual stream; f16 MFMA (16x16x32) for all GEMM-shaped compute.

typedef _Float16 h16;
typedef __attribute__((ext_vector_type(8))) _Float16 f16x8;
typedef __attribute__((ext_vector_type(4))) _Float16 f16x4;
typedef __attribute__((ext_vector_type(4))) float f32x4;

__device__ inline float wave_sum(float v){
  #pragma unroll
  for (int o=32;o;o>>=1) v += __shfl_xor(v,o);
  return v;
}
__device__ inline float wave_max(float v){
  #pragma unroll
  for (int o=32;o;o>>=1) v = fmaxf(v,__shfl_xor(v,o));
  return v;
}

// ---------------------------------------------------------------- pe table
__global__ __launch_bounds__(256) void k_pe(float* __restrict__ pe){
  int t = blockIdx.x, i = threadIdx.x;
  float two_i = (float)((i>>1)<<1);
  float dv = powf(100004.0f, two_i*(1.0f/256.0f));
  float v = (float)t / dv;
  pe[t*256+i] = (i&1) ? cosf(v) : sinf(v);
}

// ---------------------------------------------------------------- gate softmax
__global__ __launch_bounds__(64) void k_gate(const float* __restrict__ x,
    const float* __restrict__ gW, const float* __restrict__ gb,
    float* __restrict__ gate){
  int s = blockIdx.x, lane = threadIdx.x;
  __shared__ float xg[64];
  xg[lane] = x[((size_t)s*64+63)*192 + 128 + lane];
  __syncthreads();
  float a0 = gb[lane], a1 = gb[64+lane];
  #pragma unroll 4
  for (int j=0;j<64;j++){
    float xv = xg[j];
    a0 += xv*gW[j*128+lane];
    a1 += xv*gW[j*128+64+lane];
  }
  float mx = wave_max(fmaxf(a0,a1));
  float e0 = __expf(a0-mx), e1 = __expf(a1-mx);
  float sm = wave_sum(e0+e1);
  gate[s*128+lane]    = e0/sm;
  gate[s*128+64+lane] = e1/sm;
}

// ---------------------------------------------------------------- pack (H,E,DH) -> [E][256]
__global__ __launch_bounds__(256) void k_pack(const float* __restrict__ w0,
    const float* __restrict__ w1, const float* __restrict__ w2,
    const float* __restrict__ w3, const float* __restrict__ w4,
    const float* __restrict__ w5, float* __restrict__ pack){
  int g = blockIdx.x*256 + threadIdx.x;
  int mat = g>>16; int local = g&65535;
  int e = local>>8; int n = local&255;
  const float* src = (mat==0)?w0:(mat==1)?w1:(mat==2)?w2:(mat==3)?w3:(mat==4)?w4:w5;
  pack[g] = src[((n>>6)<<14) + (e<<6) + (n&63)];
}

// ---------------------------------------------------------------- generic transpose+f16
// src fp32 [K][N] row-major -> dst f16 [N][K]. grid (N/32, K/32), block 256.
__global__ __launch_bounds__(256) void k_t16(const float* __restrict__ src,
    h16* __restrict__ dst, int K, int N){
  __shared__ float tile[32][33];
  const int tid = threadIdx.x;
  const int N0 = blockIdx.x<<5, K0 = blockIdx.y<<5;
  {
    int r = tid>>3, c0 = (tid&7)<<2;
    float4 v = *(const float4*)(src + (size_t)(K0+r)*N + N0 + c0);
    tile[r][c0]=v.x; tile[r][c0+1]=v.y; tile[r][c0+2]=v.z; tile[r][c0+3]=v.w;
  }
  __syncthreads();
  {
    int r = tid>>3, c0 = (tid&7)<<2;   // r = n-local, c0 = k-local
    f16x4 o;
    o[0]=(h16)tile[c0][r]; o[1]=(h16)tile[c0+1][r];
    o[2]=(h16)tile[c0+2][r]; o[3]=(h16)tile[c0+3][r];
    *(f16x4*)(dst + (size_t)(N0+r)*K + K0 + c0) = o;
  }
}

// ---------------------------------------------------------------- MFMA GEMM
// C[M x NB-slice] = A[M x KDIM] @ Bt^T  (Bt f16 [n][k], pre-offset to slice)
// MODE 0: h16 out, ldc=128. MODE 1: embed — A = x (lda 192) gated, +pe, f32 out 256.
// MODE 2: f32 out 256.
template<int KDIM, int NB, int MODE>
__global__ __launch_bounds__(256) void k_gemm16(
    const float* __restrict__ A, int lda,
    const h16* __restrict__ Bt,
    void* __restrict__ Cv,
    const float* __restrict__ pe, const float* __restrict__ gate){
  __shared__ h16 As[64*KDIM];
  const int tid = threadIdx.x, lane = tid&63, w = tid>>6;
  const int lr = lane&15, g = lane>>4;
  const int m0 = blockIdx.x<<6;
  constexpr int CF = NB/64;        // col frags per wave
  constexpr int KT = KDIM/32;      // k steps

  // stage A tile -> f16 LDS (XOR swizzle on 16B units: idx ^= (row&7)<<3)
  if (KDIM==256){
    #pragma unroll
    for (int it=0; it<16; it++){
      int f4 = it*256 + tid;
      int row = f4>>6, c4 = (f4&63)<<2;
      float4 v = *(const float4*)(A + (size_t)(m0+row)*lda + c4);
      int idx = ((row<<8) + c4) ^ ((row&7)<<3);
      f16x4 o; o[0]=(h16)v.x; o[1]=(h16)v.y; o[2]=(h16)v.z; o[3]=(h16)v.w;
      *(f16x4*)&As[idx] = o;
    }
  } else { // KDIM==128 (embed: gated x)
    #pragma unroll
    for (int it=0; it<8; it++){
      int f4 = it*256 + tid;
      int row = f4>>5, c4 = (f4&31)<<2;
      float4 v = *(const float4*)(A + (size_t)(m0+row)*lda + c4);
      if (MODE==1){
        const float4 gg = *(const float4*)(gate + (((m0+row)>>6)<<7) + c4);
        v.x*=gg.x; v.y*=gg.y; v.z*=gg.z; v.w*=gg.w;
      }
      int idx = ((row<<7) + c4) ^ ((row&7)<<3);
      f16x4 o; o[0]=(h16)v.x; o[1]=(h16)v.y; o[2]=(h16)v.z; o[3]=(h16)v.w;
      *(f16x4*)&As[idx] = o;
    }
  }
  __syncthreads();

  f32x4 acc[4][CF];
  #pragma unroll
  for (int rf=0;rf<4;rf++)
    #pragma unroll
    for (int cf=0;cf<CF;cf++) acc[rf][cf] = (f32x4){0,0,0,0};

  #pragma unroll
  for (int kt=0; kt<KT; kt++){
    f16x8 af[4], bf[CF];
    #pragma unroll
    for (int rf=0; rf<4; rf++){
      int r = (rf<<4) + lr;
      int idx = (r*KDIM + (kt<<5) + (g<<3)) ^ ((r&7)<<3);
      af[rf] = *(const f16x8*)&As[idx];
    }
    #pragma unroll
    for (int cf=0; cf<CF; cf++){
      int n = w*(NB/4) + (cf<<4) + lr;
      bf[cf] = *(const f16x8*)(Bt + (size_t)n*KDIM + (kt<<5) + (g<<3));
    }
    #pragma unroll
    for (int rf=0; rf<4; rf++)
      #pragma unroll
      for (int cf=0; cf<CF; cf++)
        acc[rf][cf] = __builtin_amdgcn_mfma_f32_16x16x32_f16(af[rf], bf[cf], acc[rf][cf], 0,0,0);
  }

  #pragma unroll
  for (int cf=0; cf<CF; cf++){
    int col = w*(NB/4) + (cf<<4) + lr;
    #pragma unroll
    for (int rf=0; rf<4; rf++){
      #pragma unroll
      for (int i=0;i<4;i++){
        int m = m0 + (rf<<4) + (g<<2) + i;
        float v = acc[rf][cf][i];
        if (MODE==0){
          ((h16*)Cv)[(size_t)m*128 + col] = (h16)v;
        } else {
          if (MODE==1) v += pe[((m&63)<<8) + col];
          ((float*)Cv)[(size_t)m*256 + col] = v;
        }
      }
    }
  }
}

// ---------------------------------------------------------------- row LayerNorm (fp32)
__global__ __launch_bounds__(256) void k_ln(const float* __restrict__ in,
    float* __restrict__ out, const float* __restrict__ g,
    const float* __restrict__ b){
  const int wv = threadIdx.x>>6, lane = threadIdx.x&63;
  const size_t row = (size_t)blockIdx.x*4 + wv;
  float4 v = *(const float4*)(in + row*256 + (lane<<2));
  float sm = wave_sum(v.x+v.y+v.z+v.w);
  float sq = wave_sum(v.x*v.x+v.y*v.y+v.z*v.z+v.w*v.w);
  float mean = sm*(1.f/256.f);
  float rs = rsqrtf(sq*(1.f/256.f) - mean*mean + 1e-10f);
  float4 gg = *(const float4*)(g + (lane<<2));
  float4 bb = *(const float4*)(b + (lane<<2));
  float4 o;
  o.x=(v.x-mean)*rs*gg.x+bb.x; o.y=(v.y-mean)*rs*gg.y+bb.y;
  o.z=(v.z-mean)*rs*gg.z+bb.z; o.w=(v.w-mean)*rs*gg.w+bb.w;
  *(float4*)(out + row*256 + (lane<<2)) = o;
}

// ---------------------------------------------------------------- MFMA attention
// Swapped-QK flash attention, QBLK=64 (wave w: q rows 16w..16w+15), KVBLK=64, D=64.
// Q/K/V compact h16 [M][128], head col = hh*64. Out = PV/(l*8) + Resid (fp32, full width).
// NT=1: intra, grid (s,hh). NT=16: inter, grid (hh,t,qc).
template<int NT>
__global__ __launch_bounds__(256) void k_attn16(
    const h16* __restrict__ Qh, const h16* __restrict__ Kh, const h16* __restrict__ Vh,
    const float* __restrict__ Resid, float* __restrict__ Out, int hbase){
  __shared__ h16 Ks[64*64];     // [k][d], unit swizzle key = row&7
  __shared__ h16 VsT[64*64];    // [d][k], unit swizzle key = (d + (d>>3))&7
  __shared__ h16 Ps[4*16*64];   // per wave [q][k], key = q&7
  const int tid = threadIdx.x;
  const int lane = tid & 63;
  const int w = tid >> 6;
  const int lr = lane & 15;
  const int g  = lane >> 4;
  int hh, t=0, qc=0, s=0;
  if (NT==1){ s = blockIdx.x; hh = blockIdx.y; }
  else      { hh = blockIdx.x; t = blockIdx.y; qc = blockIdx.z; }
  const int ccol = hh<<6;
  const int gcol = (hbase+hh)<<6;

  // Q fragments (B-operand): lane holds Q[q = wave-local lr][d = g*8 (+32ks)]
  f16x8 qf[2];
  {
    int qr = (w<<4) + lr;
    size_t m = (NT==1) ? ((size_t)s*64 + qr) : (((size_t)qc*64 + qr)*64 + t);
    const h16* qp = Qh + m*128 + ccol + (g<<3);
    qf[0] = *(const f16x8*)qp;
    qf[1] = *(const f16x8*)(qp + 32);
  }

  f32x4 oc[4];                 // O accs: per cf, rows q=4g+i, col d=16cf+lr
  #pragma unroll
  for (int cf=0;cf<4;cf++) oc[cf] = (f32x4){0,0,0,0};
  float m_r = -1e30f, l_r = 0.f;   // softmax stats for q = lr (this wave)

  for (int kb=0; kb<NT; kb++){
    __syncthreads();
    // stage K [k][d] and V^T [d][k]
    #pragma unroll
    for (int it=0; it<2; it++){
      int u = it*256 + tid;           // 16B-unit id, 512 total
      int row = u>>3, un = u&7;
      size_t m = (NT==1) ? ((size_t)s*64 + row) : (((size_t)kb*64 + row)*64 + t);
      f16x8 kv = *(const f16x8*)(Kh + m*128 + ccol + (un<<3));
      *(f16x8*)&Ks[(row<<6) + ((un ^ (row&7))<<3)] = kv;
      f16x8 vv = *(const f16x8*)(Vh + m*128 + ccol + (un<<3));
      #pragma unroll
      for (int j=0;j<8;j++){
        int d = (un<<3) + j;
        int key = (d + un) & 7;       // (d>>3)==un
        VsT[(d<<6) + ((((row>>3) ^ key))<<3) + (row&7)] = vv[j];
      }
    }
    __syncthreads();
    // S^T = K @ Q^T : 4 accs (k-blocks), lane holds S[q=lr][k=16m+4g+i]
    f32x4 sa[4];
    #pragma unroll
    for (int mm=0;mm<4;mm++) sa[mm] = (f32x4){0,0,0,0};
    #pragma unroll
    for (int ks=0; ks<2; ks++){
      #pragma unroll
      for (int mm=0;mm<4;mm++){
        int krow = (mm<<4) + lr;
        f16x8 af = *(const f16x8*)&Ks[(krow<<6) + (((g + (ks<<2)) ^ (krow&7))<<3)];
        sa[mm] = __builtin_amdgcn_mfma_f32_16x16x32_f16(af, qf[ks], sa[mm], 0,0,0);
      }
    }
    // online softmax for q = lr
    float pmax = -1e30f;
    #pragma unroll
    for (int mm=0;mm<4;mm++)
      #pragma unroll
      for (int i=0;i<4;i++) pmax = fmaxf(pmax, sa[mm][i]);
    pmax = fmaxf(pmax, __shfl_xor(pmax, 16));
    pmax = fmaxf(pmax, __shfl_xor(pmax, 32));
    float mn = fmaxf(m_r, pmax);
    float sca = __expf(m_r - mn);
    m_r = mn;
    float ps = 0.f;
    f16x4 pv[4];
    #pragma unroll
    for (int mm=0;mm<4;mm++){
      #pragma unroll
      for (int i=0;i<4;i++){
        float p = __expf(sa[mm][i] - mn);
        ps += p;
        pv[mm][i] = (h16)p;
      }
    }
    ps += __shfl_xor(ps, 16);
    ps += __shfl_xor(ps, 32);
    l_r = l_r*sca + ps;
    // write P[q=lr][k=16m+4g .. +3] (8B vector, swizzled)
    #pragma unroll
    for (int mm=0;mm<4;mm++){
      int k0 = (mm<<4) + (g<<2);
      int unit = k0>>3, off = k0&7;
      *(f16x4*)&Ps[(w<<10) + (lr<<6) + ((unit ^ (lr&7))<<3) + off] = pv[mm];
    }
    // rescale O: row q' = 4g+i needs sca from lane with lane&15 == q'
    #pragma unroll
    for (int i=0;i<4;i++){
      float si = __shfl(sca, (g<<4) + (g<<2) + i);
      #pragma unroll
      for (int cf=0;cf<4;cf++) oc[cf][i] *= si;
    }
    // PV: O += P @ V
    #pragma unroll
    for (int ks=0; ks<2; ks++){
      f16x8 pa = *(const f16x8*)&Ps[(w<<10) + (lr<<6) + (((g + (ks<<2)) ^ (lr&7))<<3)];
      #pragma unroll
      for (int cf=0;cf<4;cf++){
        int d = (cf<<4) + lr;
        int key = (d + (d>>3)) & 7;
        f16x8 bf = *(const f16x8*)&VsT[(d<<6) + (((g + (ks<<2)) ^ key)<<3)];
        oc[cf] = __builtin_amdgcn_mfma_f32_16x16x32_f16(pa, bf, oc[cf], 0,0,0);
      }
    }
  }
  // epilogue: /(l*8) + residual
  float linv = 1.0f/(l_r*8.0f);
  #pragma unroll
  for (int i=0;i<4;i++){
    float li = __shfl(linv, (g<<4) + (g<<2) + i);
    int qr = (w<<4) + (g<<2) + i;
    size_t m = (NT==1) ? ((size_t)s*64 + qr) : (((size_t)qc*64 + qr)*64 + t);
    #pragma unroll
    for (int cf=0;cf<4;cf++){
      int d = (cf<<4) + lr;
      size_t ga = m*256 + gcol + d;
      Out[ga] = oc[cf][i]*li + Resid[ga];
    }
  }
}

// ---------------------------------------------------------------- MFMA FFN (verified r3)
__global__ __launch_bounds__(256) void k_ffn_mfma(
    const float* X, float* Out,
    const float* __restrict__ lng, const float* __restrict__ lnb,
    const h16* __restrict__ W1t, const float* __restrict__ b1,
    const h16* __restrict__ W2t, const float* __restrict__ b2){
  __shared__ h16 Xs[64*256];
  __shared__ h16 Hc[64*256];
  const int tid  = threadIdx.x;
  const int lane = tid & 63;
  const int w    = tid >> 6;
  const int r0   = blockIdx.x << 6;
  const int lr   = lane & 15;
  const int lg   = lane >> 4;

  {
    float4 gg = *(const float4*)(lng + (lane<<2));
    float4 bb = *(const float4*)(lnb + (lane<<2));
    for (int rr=0; rr<16; rr++){
      int r = (w<<4) + rr;
      float4 v = *(const float4*)(X + (size_t)(r0+r)*256 + (lane<<2));
      float sm = wave_sum(v.x+v.y+v.z+v.w);
      float sq = wave_sum(v.x*v.x+v.y*v.y+v.z*v.z+v.w*v.w);
      float mean = sm*(1.f/256.f);
      float rs = rsqrtf(sq*(1.f/256.f) - mean*mean + 1e-10f);
      f16x4 o;
      o[0]=(h16)((v.x-mean)*rs*gg.x+bb.x); o[1]=(h16)((v.y-mean)*rs*gg.y+bb.y);
      o[2]=(h16)((v.z-mean)*rs*gg.z+bb.z); o[3]=(h16)((v.w-mean)*rs*gg.w+bb.w);
      int idx = ((r<<8) + (lane<<2)) ^ ((r&7)<<3);
      *(f16x4*)&Xs[idx] = o;
    }
  }
  __syncthreads();

  f32x4 acc2[4][4];
  #pragma unroll
  for (int a=0;a<4;a++)
    #pragma unroll
    for (int b=0;b<4;b++) acc2[a][b] = (f32x4){0.f,0.f,0.f,0.f};

  for (int hc=0; hc<4; hc++){
    f32x4 acc1[4][4];
    #pragma unroll
    for (int a=0;a<4;a++)
      #pragma unroll
      for (int b=0;b<4;b++) acc1[a][b] = (f32x4){0.f,0.f,0.f,0.f};
    #pragma unroll
    for (int kt=0; kt<8; kt++){
      f16x8 af[4], bf[4];
      #pragma unroll
      for (int rf=0; rf<4; rf++){
        int r = (rf<<4) + lr;
        int idx = ((r<<8) + (kt<<5) + (lg<<3)) ^ ((r&7)<<3);
        af[rf] = *(const f16x8*)&Xs[idx];
      }
      #pragma unroll
      for (int cf=0; cf<4; cf++){
        int n = (hc<<8) + (w<<6) + (cf<<4) + lr;
        bf[cf] = *(const f16x8*)(W1t + (size_t)n*256 + (kt<<5) + (lg<<3));
      }
      #pragma unroll
      for (int rf=0; rf<4; rf++)
        #pragma unroll
        for (int cf=0; cf<4; cf++)
          acc1[rf][cf] = __builtin_amdgcn_mfma_f32_16x16x32_f16(
              af[rf], bf[cf], acc1[rf][cf], 0, 0, 0);
    }
    __syncthreads();
    #pragma unroll
    for (int cf=0; cf<4; cf++){
      int cl = (w<<6) + (cf<<4) + lr;
      float bv = b1[(hc<<8) + cl];
      #pragma unroll
      for (int rf=0; rf<4; rf++){
        #pragma unroll
        for (int i=0;i<4;i++){
          int r = (rf<<4) + (lg<<2) + i;
          float hv = fmaxf(acc1[rf][cf][i] + bv, 0.f);
          int idx = ((r<<8) + cl) ^ ((r&7)<<3);
          Hc[idx] = (h16)hv;
        }
      }
    }
    __syncthreads();
    #pragma unroll
    for (int kt=0; kt<8; kt++){
      f16x8 af[4], bf[4];
      #pragma unroll
      for (int rf=0; rf<4; rf++){
        int r = (rf<<4) + lr;
        int idx = ((r<<8) + (kt<<5) + (lg<<3)) ^ ((r&7)<<3);
        af[rf] = *(const f16x8*)&Hc[idx];
      }
      #pragma unroll
      for (int cf=0; cf<4; cf++){
        int n = (w<<6) + (cf<<4) + lr;
        bf[cf] = *(const f16x8*)(W2t + (size_t)n*1024 + (hc<<8) + (kt<<5) + (lg<<3));
      }
      #pragma unroll
      for (int rf=0; rf<4; rf++)
        #pragma unroll
        for (int cf=0; cf<4; cf++)
          acc2[rf][cf] = __builtin_amdgcn_mfma_f32_16x16x32_f16(
              af[rf], bf[cf], acc2[rf][cf], 0, 0, 0);
    }
  }
  #pragma unroll
  for (int cf=0; cf<4; cf++){
    int col = (w<<6) + (cf<<4) + lr;
    float bv = b2[col];
    #pragma unroll
    for (int rf=0; rf<4; rf++){
      #pragma unroll
      for (int i=0;i<4;i++){
        size_t r = (size_t)r0 + (rf<<4) + (lg<<2) + i;
        float res = X[r*256 + col];
        Out[r*256 + col] = acc2[rf][cf][i] + bv + res;
      }
    }
  }
}

// ---------------------------------------------------------------- final head
__global__ __launch_bounds__(256) void k_final2(const float* __restrict__ IO,
    const float* __restrict__ X1, const float* __restrict__ predW,
    const float* __restrict__ predb, float* __restrict__ out){
  const int s = blockIdx.x, tid = threadIdx.x;
  __shared__ float cur[256];
  __shared__ float lam[64];
  __shared__ float red[4];
  const int wv = tid>>6, lane = tid&63;
  cur[tid] = X1[((size_t)(s*64+63))*256 + tid];
  __syncthreads();
  float lg[16];
  for (int r=0;r<16;r++){
    int trow = wv*16+r;
    float4 xa = *(const float4*)(X1 + ((size_t)(s*64+trow))*256 + (lane<<2));
    float4 xc = *(float4*)&cur[lane<<2];
    lg[r] = wave_sum(xa.x*xc.x + xa.y*xc.y + xa.z*xc.z + xa.w*xc.w);
  }
  if (lane==0){
    #pragma unroll
    for (int r=0;r<16;r++) lam[wv*16+r] = lg[r];
  }
  __syncthreads();
  if (tid < 64){
    float v = lam[tid];
    float mx = wave_max(v);
    float p = __expf(v-mx);
    float sm = wave_sum(p);
    lam[tid] = p/sm;
  }
  __syncthreads();
  float ag = 0.f;
  for (int tt=0;tt<64;tt++)
    ag += lam[tt]*IO[((size_t)(s*64+tt))*256 + tid];
  float wsum = wave_sum(ag * predW[tid]);
  if (lane==0) red[wv] = wsum;
  __syncthreads();
  if (tid==0) out[s] = red[0]+red[1]+red[2]+red[3] + predb[0];
}

// ================================================================ launch
extern "C" void kernel_launch(void* const* d_in, const int* in_sizes, int n_in,
                              void* d_out, int out_size, void* d_ws, size_t ws_size,
                              hipStream_t stream){
  const float* x       = (const float*)d_in[0];
  const float* gate_W  = (const float*)d_in[1];
  const float* gate_b  = (const float*)d_in[2];
  const float* embed_W = (const float*)d_in[3];
  const float* ln0_g   = (const float*)d_in[4];
  const float* ln0_b   = (const float*)d_in[5];
  const float* iln_g   = (const float*)d_in[9];
  const float* iln_b   = (const float*)d_in[10];
  const float* iW1     = (const float*)d_in[11];
  const float* ib1     = (const float*)d_in[12];
  const float* iW2     = (const float*)d_in[13];
  const float* ib2     = (const float*)d_in[14];
  const float* eln1_g  = (const float*)d_in[18];
  const float* eln1_b  = (const float*)d_in[19];
  const float* eln2_g  = (const float*)d_in[20];
  const float* eln2_b  = (const float*)d_in[21];
  const float* eW1     = (const float*)d_in[22];
  const float* eb1     = (const float*)d_in[23];
  const float* eW2     = (const float*)d_in[24];
  const float* eb2     = (const float*)d_in[25];
  const float* temp_W  = (const float*)d_in[26];
  const float* pred_W  = (const float*)d_in[27];
  const float* pred_b  = (const float*)d_in[28];
  float* out = (float*)d_out;

  float* pe    = (float*)d_ws;          // 16384 f
  float* gate  = pe + 16384;            // 131072 f
  float* packW = gate + 131072;         // 6*65536 f
  h16* fQKV = (h16*)((char*)d_ws + ((size_t)4<<20));  // 6*65536
  h16* fE   = fQKV + 393216;            // [256][128]
  h16* fT   = fE + 32768;               // [256][256]
  h16* fW1i = fT + 65536;               // [1024][256]
  h16* fW2i = fW1i + 262144;            // [256][1024]
  h16* fW1e = fW2i + 262144;
  h16* fW2e = fW1e + 262144;
  const size_t MR = (size_t)65536*256, MH = (size_t)65536*128;
  float* A  = (float*)((char*)d_ws + ((size_t)8<<20));
  float* Bb = A + MR;
  h16* Qh = (h16*)(Bb + MR);
  h16* Kh = Qh + MH;
  h16* Vh = Kh + MH;                    // total: 8MB + 128MB + 48MB = 184 MB

  k_pe  <<<64,  256, 0, stream>>>(pe);
  k_gate<<<1024, 64, 0, stream>>>(x, gate_W, gate_b, gate);
  k_pack<<<1536,256, 0, stream>>>((const float*)d_in[6],(const float*)d_in[7],
      (const float*)d_in[8],(const float*)d_in[15],(const float*)d_in[16],
      (const float*)d_in[17], packW);
  for (int mat=0; mat<6; mat++)
    k_t16<<<dim3(8,8),256,0,stream>>>(packW + mat*65536, fQKV + mat*65536, 256, 256);
  k_t16<<<dim3(8,4),256,0,stream>>>(embed_W, fE, 128, 256);
  k_t16<<<dim3(8,8),256,0,stream>>>(temp_W, fT, 256, 256);
  k_t16<<<dim3(32,8),256,0,stream>>>(iW1, fW1i, 256, 1024);
  k_t16<<<dim3(8,32),256,0,stream>>>(iW2, fW2i, 1024, 256);
  k_t16<<<dim3(32,8),256,0,stream>>>(eW1, fW1e, 256, 1024);
  k_t16<<<dim3(8,32),256,0,stream>>>(eW2, fW2e, 1024, 256);

  // embed + pe -> A (fp32), then LN0 in place
  k_gemm16<128,256,1><<<1024,256,0,stream>>>(x, 192, fE, A, pe, gate);
  k_ln<<<16384,256,0,stream>>>(A, A, ln0_g, ln0_b);

  // intra attention per head pair: r -> Bb
  for (int hp=0; hp<2; hp++){
    int hb = hp*2;
    k_gemm16<256,128,0><<<1024,256,0,stream>>>(A, 256, fQKV + 0*65536 + hb*16384, Qh, nullptr, nullptr);
    k_gemm16<256,128,0><<<1024,256,0,stream>>>(A, 256, fQKV + 1*65536 + hb*16384, Kh, nullptr, nullptr);
    k_gemm16<256,128,0><<<1024,256,0,stream>>>(A, 256, fQKV + 2*65536 + hb*16384, Vh, nullptr, nullptr);
    k_attn16<1><<<dim3(1024,2),256,0,stream>>>(Qh, Kh, Vh, A, Bb, hb);
  }
  k_ffn_mfma<<<1024,256,0,stream>>>(Bb, Bb, iln_g, iln_b, fW1i, ib1, fW2i, ib2);

  // inter attention (transposed batching) per head pair; r2 -> Bb
  k_ln<<<16384,256,0,stream>>>(Bb, A, eln1_g, eln1_b);
  for (int hp=0; hp<2; hp++){
    int hb = hp*2;
    k_gemm16<256,128,0><<<1024,256,0,stream>>>(A, 256, fQKV + 3*65536 + hb*16384, Qh, nullptr, nullptr);
    k_gemm16<256,128,0><<<1024,256,0,stream>>>(A, 256, fQKV + 4*65536 + hb*16384, Kh, nullptr, nullptr);
    k_gemm16<256,128,0><<<1024,256,0,stream>>>(A, 256, fQKV + 5*65536 + hb*16384, Vh, nullptr, nullptr);
    k_attn16<16><<<dim3(2,64,16),256,0,stream>>>(Qh, Kh, Vh, Bb, Bb, hb);
  }
  k_ffn_mfma<<<1024,256,0,stream>>>(Bb, Bb, eln2_g, eln2_b, fW1e, eb1, fW2e, eb2);

  // head
  k_gemm16<256,256,2><<<1024,256,0,stream>>>(Bb, 256, fT, A, nullptr, nullptr);
  k_final2<<<1024,256,0,stream>>>(Bb, A, pred_W, pred_b, out);
}

// Round 5
// 853.939 us; speedup vs baseline: 8.1649x; 1.1473x over previous
//
#include <hip/hip_runtime.h>

// S=1024, T=64, F=128, J=64, E=256, H=4, DH=64. M = S*T = 65536 rows.
// fp32 residual stream; f16 MFMA (16x16x32) for all GEMM-shaped compute.

typedef _Float16 h16;
typedef __attribute__((ext_vector_type(8))) _Float16 f16x8;
typedef __attribute__((ext_vector_type(4))) _Float16 f16x4;
typedef __attribute__((ext_vector_type(4))) float f32x4;

__device__ inline float wave_sum(float v){
  #pragma unroll
  for (int o=32;o;o>>=1) v += __shfl_xor(v,o);
  return v;
}
__device__ inline float wave_max(float v){
  #pragma unroll
  for (int o=32;o;o>>=1) v = fmaxf(v,__shfl_xor(v,o));
  return v;
}

// ---------------------------------------------------------------- pe table
__global__ __launch_bounds__(256) void k_pe(float* __restrict__ pe){
  int t = blockIdx.x, i = threadIdx.x;
  float two_i = (float)((i>>1)<<1);
  float dv = powf(100004.0f, two_i*(1.0f/256.0f));
  float v = (float)t / dv;
  pe[t*256+i] = (i&1) ? cosf(v) : sinf(v);
}

// ---------------------------------------------------------------- gate softmax
__global__ __launch_bounds__(64) void k_gate(const float* __restrict__ x,
    const float* __restrict__ gW, const float* __restrict__ gb,
    float* __restrict__ gate){
  int s = blockIdx.x, lane = threadIdx.x;
  __shared__ float xg[64];
  xg[lane] = x[((size_t)s*64+63)*192 + 128 + lane];
  __syncthreads();
  float a0 = gb[lane], a1 = gb[64+lane];
  #pragma unroll 4
  for (int j=0;j<64;j++){
    float xv = xg[j];
    a0 += xv*gW[j*128+lane];
    a1 += xv*gW[j*128+64+lane];
  }
  float mx = wave_max(fmaxf(a0,a1));
  float e0 = __expf(a0-mx), e1 = __expf(a1-mx);
  float sm = wave_sum(e0+e1);
  gate[s*128+lane]    = e0/sm;
  gate[s*128+64+lane] = e1/sm;
}

// ---------------------------------------------------------------- all weight transposes -> f16 [n][k]
// dst layout (h16, from base): fQKV 6*65536 | fE 32768 | fT 65536 | fW1i 262144
// | fW2i 262144 | fW1e 262144 | fW2e 262144
__global__ __launch_bounds__(256) void k_t16all(
    const float* __restrict__ q1, const float* __restrict__ k1, const float* __restrict__ v1,
    const float* __restrict__ q2, const float* __restrict__ k2, const float* __restrict__ v2,
    const float* __restrict__ embed_W, const float* __restrict__ temp_W,
    const float* __restrict__ iW1, const float* __restrict__ iW2,
    const float* __restrict__ eW1, const float* __restrict__ eW2,
    h16* __restrict__ base){
  __shared__ float tile[32][33];
  const int b = blockIdx.x, tid = threadIdx.x;
  const float* src; h16* dst; int K, N, tb; bool qkv = false;
  if (b < 384){
    int mat = b>>6; tb = b&63; qkv = true; K = 256; N = 256;
    src = (mat==0)?q1:(mat==1)?k1:(mat==2)?v1:(mat==3)?q2:(mat==4)?k2:v2;
    dst = base + mat*65536;
  } else if (b < 416){ tb = b-384;  K=128;  N=256;  src=embed_W; dst=base+393216; }
  else if (b < 480){ tb = b-416;  K=256;  N=256;  src=temp_W;  dst=base+425984; }
  else if (b < 736){ tb = b-480;  K=256;  N=1024; src=iW1;     dst=base+491520; }
  else if (b < 992){ tb = b-736;  K=1024; N=256;  src=iW2;     dst=base+753664; }
  else if (b < 1248){ tb = b-992; K=256;  N=1024; src=eW1;     dst=base+1015808; }
  else               { tb = b-1248; K=1024; N=256; src=eW2;    dst=base+1277952; }
  const int nt = N>>5;
  const int N0 = (tb & (nt-1))<<5;
  const int K0 = (tb/nt)<<5;
  {
    int r = tid>>3, c0 = (tid&7)<<2;   // r = k-local, c = n-local
    int k = K0+r, n = N0+c0;
    const float* p = qkv ? (src + ((n>>6)<<14) + (k<<6) + (n&63))
                         : (src + (size_t)k*N + n);
    float4 v = *(const float4*)p;
    tile[r][c0]=v.x; tile[r][c0+1]=v.y; tile[r][c0+2]=v.z; tile[r][c0+3]=v.w;
  }
  __syncthreads();
  {
    int r = tid>>3, c0 = (tid&7)<<2;   // r = n-local, c0 = k-local
    f16x4 o;
    o[0]=(h16)tile[c0][r]; o[1]=(h16)tile[c0+1][r];
    o[2]=(h16)tile[c0+2][r]; o[3]=(h16)tile[c0+3][r];
    *(f16x4*)(dst + (size_t)(N0+r)*K + K0 + c0) = o;
  }
}

// ---------------------------------------------------------------- MFMA GEMM
// C[M x NB-slice] = A[M x KDIM] @ Bt^T (Bt f16 [n][k]).
// MODE 0: h16 out ldc=128. MODE 1: embed (A=x lda192, gated, +pe, f32 out 256).
// MODE 2: f32 out 256. blockIdx.y selects matrix: Bt += y*bstride, C += y*cstride.
template<int KDIM, int NB, int MODE>
__global__ __launch_bounds__(256) void k_gemm16(
    const float* __restrict__ A, int lda,
    const h16* __restrict__ Bt,
    void* __restrict__ Cv,
    const float* __restrict__ pe, const float* __restrict__ gate,
    size_t bstride, size_t cstride){
  __shared__ h16 As[64*KDIM];
  const int tid = threadIdx.x, lane = tid&63, w = tid>>6;
  const int lr = lane&15, g = lane>>4;
  const int m0 = blockIdx.x<<6;
  Bt += (size_t)blockIdx.y * bstride;
  constexpr int CF = NB/64;
  constexpr int KT = KDIM/32;

  if (KDIM==256){
    #pragma unroll
    for (int it=0; it<16; it++){
      int f4 = it*256 + tid;
      int row = f4>>6, c4 = (f4&63)<<2;
      float4 v = *(const float4*)(A + (size_t)(m0+row)*lda + c4);
      int idx = ((row<<8) + c4) ^ ((row&7)<<3);
      f16x4 o; o[0]=(h16)v.x; o[1]=(h16)v.y; o[2]=(h16)v.z; o[3]=(h16)v.w;
      *(f16x4*)&As[idx] = o;
    }
  } else { // KDIM==128 (embed: gated x)
    #pragma unroll
    for (int it=0; it<8; it++){
      int f4 = it*256 + tid;
      int row = f4>>5, c4 = (f4&31)<<2;
      float4 v = *(const float4*)(A + (size_t)(m0+row)*lda + c4);
      if (MODE==1){
        const float4 gg = *(const float4*)(gate + (((m0+row)>>6)<<7) + c4);
        v.x*=gg.x; v.y*=gg.y; v.z*=gg.z; v.w*=gg.w;
      }
      int idx = ((row<<7) + c4) ^ ((row&7)<<3);
      f16x4 o; o[0]=(h16)v.x; o[1]=(h16)v.y; o[2]=(h16)v.z; o[3]=(h16)v.w;
      *(f16x4*)&As[idx] = o;
    }
  }
  __syncthreads();

  f32x4 acc[4][CF];
  #pragma unroll
  for (int rf=0;rf<4;rf++)
    #pragma unroll
    for (int cf=0;cf<CF;cf++) acc[rf][cf] = (f32x4){0,0,0,0};

  #pragma unroll
  for (int kt=0; kt<KT; kt++){
    f16x8 af[4], bf[CF];
    #pragma unroll
    for (int rf=0; rf<4; rf++){
      int r = (rf<<4) + lr;
      int idx = (r*KDIM + (kt<<5) + (g<<3)) ^ ((r&7)<<3);
      af[rf] = *(const f16x8*)&As[idx];
    }
    #pragma unroll
    for (int cf=0; cf<CF; cf++){
      int n = w*(NB/4) + (cf<<4) + lr;
      bf[cf] = *(const f16x8*)(Bt + (size_t)n*KDIM + (kt<<5) + (g<<3));
    }
    #pragma unroll
    for (int rf=0; rf<4; rf++)
      #pragma unroll
      for (int cf=0; cf<CF; cf++)
        acc[rf][cf] = __builtin_amdgcn_mfma_f32_16x16x32_f16(af[rf], bf[cf], acc[rf][cf], 0,0,0);
  }

  #pragma unroll
  for (int cf=0; cf<CF; cf++){
    int col = w*(NB/4) + (cf<<4) + lr;
    #pragma unroll
    for (int rf=0; rf<4; rf++){
      #pragma unroll
      for (int i=0;i<4;i++){
        int m = m0 + (rf<<4) + (g<<2) + i;
        float v = acc[rf][cf][i];
        if (MODE==0){
          ((h16*)Cv)[(size_t)blockIdx.y*cstride + (size_t)m*128 + col] = (h16)v;
        } else {
          if (MODE==1) v += pe[((m&63)<<8) + col];
          ((float*)Cv)[(size_t)m*256 + col] = v;
        }
      }
    }
  }
}

// ---------------------------------------------------------------- row LayerNorm (fp32)
__global__ __launch_bounds__(256) void k_ln(const float* __restrict__ in,
    float* __restrict__ out, const float* __restrict__ g,
    const float* __restrict__ b){
  const int wv = threadIdx.x>>6, lane = threadIdx.x&63;
  const size_t row = (size_t)blockIdx.x*4 + wv;
  float4 v = *(const float4*)(in + row*256 + (lane<<2));
  float sm = wave_sum(v.x+v.y+v.z+v.w);
  float sq = wave_sum(v.x*v.x+v.y*v.y+v.z*v.z+v.w*v.w);
  float mean = sm*(1.f/256.f);
  float rs = rsqrtf(sq*(1.f/256.f) - mean*mean + 1e-10f);
  float4 gg = *(const float4*)(g + (lane<<2));
  float4 bb = *(const float4*)(b + (lane<<2));
  float4 o;
  o.x=(v.x-mean)*rs*gg.x+bb.x; o.y=(v.y-mean)*rs*gg.y+bb.y;
  o.z=(v.z-mean)*rs*gg.z+bb.z; o.w=(v.w-mean)*rs*gg.w+bb.w;
  *(float4*)(out + row*256 + (lane<<2)) = o;
}

// ---------------------------------------------------------------- MFMA attention (verified r4)
template<int NT>
__global__ __launch_bounds__(256) void k_attn16(
    const h16* __restrict__ Qh, const h16* __restrict__ Kh, const h16* __restrict__ Vh,
    const float* __restrict__ Resid, float* __restrict__ Out, int hbase){
  __shared__ h16 Ks[64*64];
  __shared__ h16 VsT[64*64];
  __shared__ h16 Ps[4*16*64];
  const int tid = threadIdx.x;
  const int lane = tid & 63;
  const int w = tid >> 6;
  const int lr = lane & 15;
  const int g  = lane >> 4;
  int hh, t=0, qc=0, s=0;
  if (NT==1){ s = blockIdx.x; hh = blockIdx.y; }
  else      { hh = blockIdx.x; t = blockIdx.y; qc = blockIdx.z; }
  const int ccol = hh<<6;
  const int gcol = (hbase+hh)<<6;

  f16x8 qf[2];
  {
    int qr = (w<<4) + lr;
    size_t m = (NT==1) ? ((size_t)s*64 + qr) : (((size_t)qc*64 + qr)*64 + t);
    const h16* qp = Qh + m*128 + ccol + (g<<3);
    qf[0] = *(const f16x8*)qp;
    qf[1] = *(const f16x8*)(qp + 32);
  }

  f32x4 oc[4];
  #pragma unroll
  for (int cf=0;cf<4;cf++) oc[cf] = (f32x4){0,0,0,0};
  float m_r = -1e30f, l_r = 0.f;

  for (int kb=0; kb<NT; kb++){
    __syncthreads();
    #pragma unroll
    for (int it=0; it<2; it++){
      int u = it*256 + tid;
      int row = u>>3, un = u&7;
      size_t m = (NT==1) ? ((size_t)s*64 + row) : (((size_t)kb*64 + row)*64 + t);
      f16x8 kv = *(const f16x8*)(Kh + m*128 + ccol + (un<<3));
      *(f16x8*)&Ks[(row<<6) + ((un ^ (row&7))<<3)] = kv;
      f16x8 vv = *(const f16x8*)(Vh + m*128 + ccol + (un<<3));
      #pragma unroll
      for (int j=0;j<8;j++){
        int d = (un<<3) + j;
        int key = (d + un) & 7;
        VsT[(d<<6) + ((((row>>3) ^ key))<<3) + (row&7)] = vv[j];
      }
    }
    __syncthreads();
    f32x4 sa[4];
    #pragma unroll
    for (int mm=0;mm<4;mm++) sa[mm] = (f32x4){0,0,0,0};
    #pragma unroll
    for (int ks=0; ks<2; ks++){
      #pragma unroll
      for (int mm=0;mm<4;mm++){
        int krow = (mm<<4) + lr;
        f16x8 af = *(const f16x8*)&Ks[(krow<<6) + (((g + (ks<<2)) ^ (krow&7))<<3)];
        sa[mm] = __builtin_amdgcn_mfma_f32_16x16x32_f16(af, qf[ks], sa[mm], 0,0,0);
      }
    }
    float pmax = -1e30f;
    #pragma unroll
    for (int mm=0;mm<4;mm++)
      #pragma unroll
      for (int i=0;i<4;i++) pmax = fmaxf(pmax, sa[mm][i]);
    pmax = fmaxf(pmax, __shfl_xor(pmax, 16));
    pmax = fmaxf(pmax, __shfl_xor(pmax, 32));
    float mn = fmaxf(m_r, pmax);
    float sca = __expf(m_r - mn);
    m_r = mn;
    float ps = 0.f;
    f16x4 pv[4];
    #pragma unroll
    for (int mm=0;mm<4;mm++){
      #pragma unroll
      for (int i=0;i<4;i++){
        float p = __expf(sa[mm][i] - mn);
        ps += p;
        pv[mm][i] = (h16)p;
      }
    }
    ps += __shfl_xor(ps, 16);
    ps += __shfl_xor(ps, 32);
    l_r = l_r*sca + ps;
    #pragma unroll
    for (int mm=0;mm<4;mm++){
      int k0 = (mm<<4) + (g<<2);
      int unit = k0>>3, off = k0&7;
      *(f16x4*)&Ps[(w<<10) + (lr<<6) + ((unit ^ (lr&7))<<3) + off] = pv[mm];
    }
    #pragma unroll
    for (int i=0;i<4;i++){
      float si = __shfl(sca, (g<<4) + (g<<2) + i);
      #pragma unroll
      for (int cf=0;cf<4;cf++) oc[cf][i] *= si;
    }
    #pragma unroll
    for (int ks=0; ks<2; ks++){
      f16x8 pa = *(const f16x8*)&Ps[(w<<10) + (lr<<6) + (((g + (ks<<2)) ^ (lr&7))<<3)];
      #pragma unroll
      for (int cf=0;cf<4;cf++){
        int d = (cf<<4) + lr;
        int key = (d + (d>>3)) & 7;
        f16x8 bf = *(const f16x8*)&VsT[(d<<6) + (((g + (ks<<2)) ^ key)<<3)];
        oc[cf] = __builtin_amdgcn_mfma_f32_16x16x32_f16(pa, bf, oc[cf], 0,0,0);
      }
    }
  }
  float linv = 1.0f/(l_r*8.0f);
  #pragma unroll
  for (int i=0;i<4;i++){
    float li = __shfl(linv, (g<<4) + (g<<2) + i);
    int qr = (w<<4) + (g<<2) + i;
    size_t m = (NT==1) ? ((size_t)s*64 + qr) : (((size_t)qc*64 + qr)*64 + t);
    #pragma unroll
    for (int cf=0;cf<4;cf++){
      int d = (cf<<4) + lr;
      size_t ga = m*256 + gcol + d;
      Out[ga] = oc[cf][i]*li + Resid[ga];
    }
  }
}

// ---------------------------------------------------------------- MFMA FFN, 8 waves
// Out = X + relu(LN(X)@W1+b1)@W2 + b2. 64 rows/block, 512 thr; wave w owns
// 32 cols of each GEMM. Hidden in 4 chunks of 256.
__global__ __launch_bounds__(512) void k_ffn2(
    const float* X, float* Out,
    const float* __restrict__ lng, const float* __restrict__ lnb,
    const h16* __restrict__ W1t, const float* __restrict__ b1,
    const h16* __restrict__ W2t, const float* __restrict__ b2){
  __shared__ h16 Xs[64*256];
  __shared__ h16 Hc[64*256];
  const int tid  = threadIdx.x;
  const int lane = tid & 63;
  const int w    = tid >> 6;      // 0..7
  const int r0   = blockIdx.x << 6;
  const int lr   = lane & 15;
  const int g    = lane >> 4;

  {
    float4 gg = *(const float4*)(lng + (lane<<2));
    float4 bb = *(const float4*)(lnb + (lane<<2));
    #pragma unroll
    for (int rr=0; rr<8; rr++){
      int r = (w<<3) + rr;
      float4 v = *(const float4*)(X + (size_t)(r0+r)*256 + (lane<<2));
      float sm = wave_sum(v.x+v.y+v.z+v.w);
      float sq = wave_sum(v.x*v.x+v.y*v.y+v.z*v.z+v.w*v.w);
      float mean = sm*(1.f/256.f);
      float rs = rsqrtf(sq*(1.f/256.f) - mean*mean + 1e-10f);
      f16x4 o;
      o[0]=(h16)((v.x-mean)*rs*gg.x+bb.x); o[1]=(h16)((v.y-mean)*rs*gg.y+bb.y);
      o[2]=(h16)((v.z-mean)*rs*gg.z+bb.z); o[3]=(h16)((v.w-mean)*rs*gg.w+bb.w);
      int idx = ((r<<8) + (lane<<2)) ^ ((r&7)<<3);
      *(f16x4*)&Xs[idx] = o;
    }
  }
  __syncthreads();

  f32x4 acc2[4][2];
  #pragma unroll
  for (int a=0;a<4;a++){ acc2[a][0]=(f32x4){0,0,0,0}; acc2[a][1]=(f32x4){0,0,0,0}; }

  for (int hc=0; hc<4; hc++){
    f32x4 acc1[4][2];
    #pragma unroll
    for (int a=0;a<4;a++){ acc1[a][0]=(f32x4){0,0,0,0}; acc1[a][1]=(f32x4){0,0,0,0}; }
    #pragma unroll
    for (int kt=0; kt<8; kt++){
      f16x8 af[4], bf[2];
      #pragma unroll
      for (int rf=0; rf<4; rf++){
        int r = (rf<<4) + lr;
        int idx = ((r<<8) + (kt<<5) + (g<<3)) ^ ((r&7)<<3);
        af[rf] = *(const f16x8*)&Xs[idx];
      }
      #pragma unroll
      for (int cf=0; cf<2; cf++){
        int n = (hc<<8) + (w<<5) + (cf<<4) + lr;
        bf[cf] = *(const f16x8*)(W1t + (size_t)n*256 + (kt<<5) + (g<<3));
      }
      #pragma unroll
      for (int rf=0; rf<4; rf++)
        #pragma unroll
        for (int cf=0; cf<2; cf++)
          acc1[rf][cf] = __builtin_amdgcn_mfma_f32_16x16x32_f16(
              af[rf], bf[cf], acc1[rf][cf], 0, 0, 0);
    }
    __syncthreads();   // all waves' prior-chunk GEMM2 reads of Hc complete
    #pragma unroll
    for (int cf=0; cf<2; cf++){
      int cl = (w<<5) + (cf<<4) + lr;
      float bv = b1[(hc<<8) + cl];
      #pragma unroll
      for (int rf=0; rf<4; rf++){
        #pragma unroll
        for (int i=0;i<4;i++){
          int r = (rf<<4) + (g<<2) + i;
          float hv = fmaxf(acc1[rf][cf][i] + bv, 0.f);
          int idx = ((r<<8) + cl) ^ ((r&7)<<3);
          Hc[idx] = (h16)hv;
        }
      }
    }
    __syncthreads();
    #pragma unroll
    for (int kt=0; kt<8; kt++){
      f16x8 af[4], bf[2];
      #pragma unroll
      for (int rf=0; rf<4; rf++){
        int r = (rf<<4) + lr;
        int idx = ((r<<8) + (kt<<5) + (g<<3)) ^ ((r&7)<<3);
        af[rf] = *(const f16x8*)&Hc[idx];
      }
      #pragma unroll
      for (int cf=0; cf<2; cf++){
        int n = (w<<5) + (cf<<4) + lr;
        bf[cf] = *(const f16x8*)(W2t + (size_t)n*1024 + (hc<<8) + (kt<<5) + (g<<3));
      }
      #pragma unroll
      for (int rf=0; rf<4; rf++)
        #pragma unroll
        for (int cf=0; cf<2; cf++)
          acc2[rf][cf] = __builtin_amdgcn_mfma_f32_16x16x32_f16(
              af[rf], bf[cf], acc2[rf][cf], 0, 0, 0);
    }
  }
  #pragma unroll
  for (int cf=0; cf<2; cf++){
    int col = (w<<5) + (cf<<4) + lr;
    float bv = b2[col];
    #pragma unroll
    for (int rf=0; rf<4; rf++){
      #pragma unroll
      for (int i=0;i<4;i++){
        size_t r = (size_t)r0 + (rf<<4) + (g<<2) + i;
        float res = X[r*256 + col];
        Out[r*256 + col] = acc2[rf][cf][i] + bv + res;
      }
    }
  }
}

// ---------------------------------------------------------------- final head
__global__ __launch_bounds__(256) void k_final2(const float* __restrict__ IO,
    const float* __restrict__ X1, const float* __restrict__ predW,
    const float* __restrict__ predb, float* __restrict__ out){
  const int s = blockIdx.x, tid = threadIdx.x;
  __shared__ float cur[256];
  __shared__ float lam[64];
  __shared__ float red[4];
  const int wv = tid>>6, lane = tid&63;
  cur[tid] = X1[((size_t)(s*64+63))*256 + tid];
  __syncthreads();
  float lg[16];
  for (int r=0;r<16;r++){
    int trow = wv*16+r;
    float4 xa = *(const float4*)(X1 + ((size_t)(s*64+trow))*256 + (lane<<2));
    float4 xc = *(float4*)&cur[lane<<2];
    lg[r] = wave_sum(xa.x*xc.x + xa.y*xc.y + xa.z*xc.z + xa.w*xc.w);
  }
  if (lane==0){
    #pragma unroll
    for (int r=0;r<16;r++) lam[wv*16+r] = lg[r];
  }
  __syncthreads();
  if (tid < 64){
    float v = lam[tid];
    float mx = wave_max(v);
    float p = __expf(v-mx);
    float sm = wave_sum(p);
    lam[tid] = p/sm;
  }
  __syncthreads();
  float ag = 0.f;
  for (int tt=0;tt<64;tt++)
    ag += lam[tt]*IO[((size_t)(s*64+tt))*256 + tid];
  float wsum = wave_sum(ag * predW[tid]);
  if (lane==0) red[wv] = wsum;
  __syncthreads();
  if (tid==0) out[s] = red[0]+red[1]+red[2]+red[3] + predb[0];
}

// ================================================================ launch
extern "C" void kernel_launch(void* const* d_in, const int* in_sizes, int n_in,
                              void* d_out, int out_size, void* d_ws, size_t ws_size,
                              hipStream_t stream){
  const float* x       = (const float*)d_in[0];
  const float* gate_W  = (const float*)d_in[1];
  const float* gate_b  = (const float*)d_in[2];
  const float* embed_W = (const float*)d_in[3];
  const float* ln0_g   = (const float*)d_in[4];
  const float* ln0_b   = (const float*)d_in[5];
  const float* iln_g   = (const float*)d_in[9];
  const float* iln_b   = (const float*)d_in[10];
  const float* iW1     = (const float*)d_in[11];
  const float* ib1     = (const float*)d_in[12];
  const float* iW2     = (const float*)d_in[13];
  const float* ib2     = (const float*)d_in[14];
  const float* eln1_g  = (const float*)d_in[18];
  const float* eln1_b  = (const float*)d_in[19];
  const float* eln2_g  = (const float*)d_in[20];
  const float* eln2_b  = (const float*)d_in[21];
  const float* eW1     = (const float*)d_in[22];
  const float* eb1     = (const float*)d_in[23];
  const float* eW2     = (const float*)d_in[24];
  const float* eb2     = (const float*)d_in[25];
  const float* temp_W  = (const float*)d_in[26];
  const float* pred_W  = (const float*)d_in[27];
  const float* pred_b  = (const float*)d_in[28];
  float* out = (float*)d_out;

  float* pe    = (float*)d_ws;          // 16384 f
  float* gate  = pe + 16384;            // 131072 f
  h16* fQKV = (h16*)((char*)d_ws + ((size_t)4<<20));
  h16* fE   = fQKV + 393216;
  h16* fT   = fE + 32768;
  h16* fW1i = fT + 65536;
  h16* fW2i = fW1i + 262144;
  h16* fW1e = fW2i + 262144;
  h16* fW2e = fW1e + 262144;
  const size_t MR = (size_t)65536*256, MH = (size_t)65536*128;
  float* A  = (float*)((char*)d_ws + ((size_t)8<<20));
  float* Bb = A + MR;
  h16* Qh = (h16*)(Bb + MR);            // Qh,Kh,Vh consecutive (stride MH)
  h16* Kh = Qh + MH;
  h16* Vh = Kh + MH;

  k_pe  <<<64,  256, 0, stream>>>(pe);
  k_gate<<<1024, 64, 0, stream>>>(x, gate_W, gate_b, gate);
  k_t16all<<<1504,256,0,stream>>>(
      (const float*)d_in[6],(const float*)d_in[7],(const float*)d_in[8],
      (const float*)d_in[15],(const float*)d_in[16],(const float*)d_in[17],
      embed_W, temp_W, iW1, iW2, eW1, eW2, fQKV);

  // embed + pe -> A (fp32), then LN0 in place
  k_gemm16<128,256,1><<<1024,256,0,stream>>>(x, 192, fE, A, pe, gate, 0, 0);
  k_ln<<<16384,256,0,stream>>>(A, A, ln0_g, ln0_b);

  // intra attention per head pair: r -> Bb
  for (int hp=0; hp<2; hp++){
    int hb = hp*2;
    k_gemm16<256,128,0><<<dim3(1024,3),256,0,stream>>>(
        A, 256, fQKV + hb*16384, Qh, nullptr, nullptr, 65536, MH);
    k_attn16<1><<<dim3(1024,2),256,0,stream>>>(Qh, Kh, Vh, A, Bb, hb);
  }
  k_ffn2<<<1024,512,0,stream>>>(Bb, Bb, iln_g, iln_b, fW1i, ib1, fW2i, ib2);

  // inter attention (transposed batching) per head pair; r2 -> Bb
  k_ln<<<16384,256,0,stream>>>(Bb, A, eln1_g, eln1_b);
  for (int hp=0; hp<2; hp++){
    int hb = hp*2;
    k_gemm16<256,128,0><<<dim3(1024,3),256,0,stream>>>(
        A, 256, fQKV + 3*65536 + hb*16384, Qh, nullptr, nullptr, 65536, MH);
    k_attn16<16><<<dim3(2,64,16),256,0,stream>>>(Qh, Kh, Vh, Bb, Bb, hb);
  }
  k_ffn2<<<1024,512,0,stream>>>(Bb, Bb, eln2_g, eln2_b, fW1e, eb1, fW2e, eb2);

  // head
  k_gemm16<256,256,2><<<1024,256,0,stream>>>(Bb, 256, fT, A, nullptr, nullptr, 0, 0);
  k_final2<<<1024,256,0,stream>>>(Bb, A, pred_W, pred_b, out);
}